// Round 14
// baseline (150.181 us; speedup 1.0000x reference)
//
#include <hip/hip_runtime.h>
#include <hip/hip_bf16.h>

#define K49 49

typedef short bf16x8 __attribute__((ext_vector_type(8)));
typedef float f32x4 __attribute__((ext_vector_type(4)));

__device__ __forceinline__ short f2bf(float x) {
    __hip_bfloat16 h = __float2bfloat16(x);
    return __builtin_bit_cast(short, h);
}
__device__ __forceinline__ float bf2f(short s) {
    unsigned u = ((unsigned)(unsigned short)s) << 16;
    return __builtin_bit_cast(float, u);
}

// ==================== weight packing (device fns) ====================
__device__ __forceinline__ void d_pack_ow1(
    const int gid, const float* __restrict__ OW, short* __restrict__ OWbf)
{
    const int ni = gid & 15;
    int t = gid >> 4;
    const int kg = t & 3;  t >>= 2;
    const int kb = t & 31; t >>= 5;
    const int nt = t % 7;
    const int d  = t / 7;
    const int oc = nt * 16 + ni;
    short h[8];
    if (oc < 98) {
        const int c0 = kb * 32 + kg * 8;
        #pragma unroll
        for (int j = 0; j < 8; ++j)
            h[j] = f2bf(OW[((size_t)d * 1024 + c0 + j) * 98 + oc]);
    } else {
        #pragma unroll
        for (int j = 0; j < 8; ++j) h[j] = 0;
    }
    *(bf16x8*)(OWbf + (size_t)gid * 8) = *(bf16x8*)h;
}

template<int C, int F>
__device__ __forceinline__ void d_pack_w(
    const int gid, const float* __restrict__ Wt, short* __restrict__ Wf)
{
    constexpr int KB = C / 32;
    constexpr int NT = F / 16;
    constexpr int PLANE = 49 * NT * KB * 4 * 16 * 8;   // shorts
    const int ni = gid & 15;
    int t = gid >> 4;
    const int kg = t & 3; t >>= 2;
    const int kb = t % KB; t /= KB;
    const int nt = t % NT;
    const int d  = t / NT;
    const int f = nt * 16 + ni;
    const int c0 = kb * 32 + kg * 8;
    short hi[8], lo[8];
    #pragma unroll
    for (int j = 0; j < 8; ++j) {
        const float v = Wt[((size_t)d * C + c0 + j) * F + f];
        hi[j] = f2bf(v);
        lo[j] = f2bf(v - bf2f(hi[j]));
    }
    *(bf16x8*)(Wf + (size_t)gid * 8) = *(bf16x8*)hi;
    *(bf16x8*)(Wf + PLANE + (size_t)gid * 8) = *(bf16x8*)lo;
}

template<int C>
__device__ __forceinline__ void d_pack_owf(
    const int gid, const float* __restrict__ OW, short* __restrict__ OWf)
{
    const int j = gid & 7;
    int t = gid >> 3;
    const int fi = t & 63; t >>= 6;
    const int nt = t % 7;
    const int kbg = t / 7;
    const int ni = fi & 15, kg = fi >> 4;

    int cum1, cum2, cum3;
    if (C == 64)      { cum1 = 18; cum2 = 42; cum3 = 66; }
    else if (C == 32) { cum1 = 9;  cum2 = 21; cum3 = 33; }
    else              { cum1 = 5;  cum2 = 11; cum3 = 17; }
    int cls, kb0;
    if (kbg < cum1)      { cls = 0; kb0 = 0; }
    else if (kbg < cum2) { cls = 1; kb0 = cum1; }
    else if (kbg < cum3) { cls = 2; kb0 = cum2; }
    else                 { cls = 3; kb0 = cum3; }
    const int kbl = kbg - kb0;
    const int pi = cls >> 1, rho = cls & 1;
    const int NRc = pi ? 4 : 3, NCc = rho ? 4 : 3;
    const int T = NRc * NCc;

    const int k = kbl * 32 + kg * 8 + j;
    const int tl = k / C, c = k - tl * C;
    const int oc = nt * 16 + ni;
    float v = 0.f;
    if (tl < T && oc < 98) {
        const int iy = tl / NCc, ix = tl - iy * NCc;
        const int d = (1 - pi + 2 * iy) * 7 + (1 - rho + 2 * ix);
        v = OW[((size_t)d * C + c) * 98 + oc];
    }
    OWf[gid] = f2bf(v);
}

// ==================== mega prep kernel: dense+cvt AND all weight packs =====
// Xf layout (bf16): [plane(2)][mtile(16)][kb(32)][kg(4)][mi(16)][8]
__global__ __launch_bounds__(256) void k_prep(
    const float* __restrict__ z, const float* __restrict__ Wd,
    const float* __restrict__ bd, short* __restrict__ Xf,
    const float* __restrict__ ow1, const float* __restrict__ w1,
    const float* __restrict__ ow2, const float* __restrict__ w2,
    const float* __restrict__ ow3, const float* __restrict__ w3,
    const float* __restrict__ ow4,
    short* OWbf, short* W1f, short* OWf2, short* W2f,
    short* OWf3, short* W3f, short* OWf4)
{
    const int bid0 = blockIdx.x;
    const int tid = threadIdx.x;
    __shared__ float zs[256];
    if (bid0 < 512) {
        const int D = 131072;
        zs[tid] = z[tid];
        __syncthreads();
        const int n = bid0 * 256 + tid;
        const float bb = bd[n];
        float a0 = bb, a1 = bb;
        #pragma unroll 8
        for (int kk = 0; kk < 128; ++kk) {
            const float w = Wd[kk * D + n];
            a0 = fmaf(zs[kk], w, a0);
            a1 = fmaf(zs[128 + kk], w, a1);
        }
        a0 = fmaxf(a0, 0.f);
        a1 = fmaxf(a1, 0.f);
        const int c = n & 1023;
        const int m0 = n >> 10;
        const int kb = c >> 5, kg = (c >> 3) & 3, j = c & 7;
        const size_t base = ((size_t)kb * 4 + kg) * 16 * 8 + j;
        {
            const size_t dst = ((size_t)(m0 >> 4) * 2048) * 8 + base + (size_t)(m0 & 15) * 8;
            const short h = f2bf(a0);
            Xf[dst] = h;
            Xf[262144 + dst] = f2bf(a0 - bf2f(h));
        }
        {
            const int m1 = m0 + 128;
            const size_t dst = ((size_t)(m1 >> 4) * 2048) * 8 + base + (size_t)(m1 & 15) * 8;
            const short h = f2bf(a1);
            Xf[dst] = h;
            Xf[262144 + dst] = f2bf(a1 - bf2f(h));
        }
        return;
    }
    const int bid = bid0 - 512;
    if (bid < 2744)      d_pack_ow1((bid) * 256 + tid, ow1, OWbf);
    else if (bid < 4312) d_pack_w<1024, 64>((bid - 2744) * 256 + tid, w1, W1f);
    else if (bid < 5684) d_pack_owf<64>((bid - 4312) * 256 + tid, ow2, OWf2);
    else if (bid < 5733) d_pack_w<64, 32>((bid - 5684) * 256 + tid, w2, W2f);
    else if (bid < 6419) d_pack_owf<32>((bid - 5733) * 256 + tid, ow3, OWf3);
    else if (bid < 6432) { const int g = (bid - 6419) * 256 + tid; if (g < 3136) d_pack_w<32, 16>(g, w3, W3f); }
    else                 d_pack_owf<16>((bid - 6432) * 256 + tid, ow4, OWf4);
}

// ============ stage-1 GEMMs, K-split x4 + 2-mtile B-reuse: grid 784 =====
// Zp partial: [ks][49][256][98]; Y1 partial: [ks][49][256][64]
// work = ks*196 + by*2 + x; wave handles mtiles x*8+wv and x*8+wv+4.
__global__ __launch_bounds__(256) void k_gemms1(
    const short* __restrict__ Xf, const short* __restrict__ OWbf,
    const short* __restrict__ W1f,
    float* __restrict__ Zp, float* __restrict__ Y1)
{
    const int tid = threadIdx.x;
    const int wv = tid >> 6;
    const int l  = tid & 63;
    const int l15 = l & 15, l4 = l >> 4;

    // XCD-aware: consecutive works (B-sharing x-pairs) on one XCD chunk
    const int bid = blockIdx.x;                  // 0..783
    const int work = (bid & 7) * 98 + (bid >> 3);
    const int ks   = work / 196;
    const int rem  = work - ks * 196;
    const int by   = rem >> 1;
    const int x    = rem & 1;

    const int mt0 = x * 8 + wv;
    const int mt1 = mt0 + 4;
    const int kb0 = ks * 8;
    const int lofs = l4 * 16 + l15;

    const bf16x8* Ah0 = (const bf16x8*)Xf + (size_t)mt0 * 2048 + lofs;
    const bf16x8* Ah1 = (const bf16x8*)Xf + (size_t)mt1 * 2048 + lofs;
    const int m00 = mt0 * 16 + l4 * 4;
    const int m01 = mt1 * 16 + l4 * 4;

    if (by < 49) {
        const int d = by;
        const bf16x8* Bb = (const bf16x8*)OWbf + (size_t)d * 7 * 2048 + lofs;
        f32x4 acc0[7], acc1[7];
        #pragma unroll
        for (int nt = 0; nt < 7; ++nt) {
            acc0[nt] = (f32x4){0.f, 0.f, 0.f, 0.f};
            acc1[nt] = (f32x4){0.f, 0.f, 0.f, 0.f};
        }
        #pragma unroll
        for (int i = 0; i < 8; ++i) {
            const int kb = kb0 + i;
            const bf16x8 ah0 = Ah0[kb * 64];
            const bf16x8 al0 = Ah0[32768 + kb * 64];
            const bf16x8 ah1 = Ah1[kb * 64];
            const bf16x8 al1 = Ah1[32768 + kb * 64];
            #pragma unroll
            for (int nt = 0; nt < 7; ++nt) {
                const bf16x8 b = Bb[(size_t)nt * 2048 + kb * 64];
                acc0[nt] = __builtin_amdgcn_mfma_f32_16x16x32_bf16(ah0, b, acc0[nt], 0, 0, 0);
                acc0[nt] = __builtin_amdgcn_mfma_f32_16x16x32_bf16(al0, b, acc0[nt], 0, 0, 0);
                acc1[nt] = __builtin_amdgcn_mfma_f32_16x16x32_bf16(ah1, b, acc1[nt], 0, 0, 0);
                acc1[nt] = __builtin_amdgcn_mfma_f32_16x16x32_bf16(al1, b, acc1[nt], 0, 0, 0);
            }
        }
        float* Zo = Zp + (size_t)ks * 1229312;
        #pragma unroll
        for (int nt = 0; nt < 7; ++nt) {
            const int oc = nt * 16 + l15;
            if (oc < 98) {
                #pragma unroll
                for (int r = 0; r < 4; ++r) {
                    Zo[((size_t)d * 256 + m00 + r) * 98 + oc] = acc0[nt][r];
                    Zo[((size_t)d * 256 + m01 + r) * 98 + oc] = acc1[nt][r];
                }
            }
        }
    } else {
        const int d = by - 49;
        const bf16x8* Bh = (const bf16x8*)W1f + (size_t)d * 4 * 2048 + lofs;
        const bf16x8* Bl = Bh + 401408;
        f32x4 acc0[4], acc1[4];
        #pragma unroll
        for (int nt = 0; nt < 4; ++nt) {
            acc0[nt] = (f32x4){0.f, 0.f, 0.f, 0.f};
            acc1[nt] = (f32x4){0.f, 0.f, 0.f, 0.f};
        }
        #pragma unroll
        for (int i = 0; i < 8; ++i) {
            const int kb = kb0 + i;
            const bf16x8 ah0 = Ah0[kb * 64];
            const bf16x8 al0 = Ah0[32768 + kb * 64];
            const bf16x8 ah1 = Ah1[kb * 64];
            const bf16x8 al1 = Ah1[32768 + kb * 64];
            #pragma unroll
            for (int nt = 0; nt < 4; ++nt) {
                const bf16x8 bh = Bh[nt * 2048 + kb * 64];
                const bf16x8 bl = Bl[nt * 2048 + kb * 64];
                acc0[nt] = __builtin_amdgcn_mfma_f32_16x16x32_bf16(ah0, bh, acc0[nt], 0, 0, 0);
                acc0[nt] = __builtin_amdgcn_mfma_f32_16x16x32_bf16(ah0, bl, acc0[nt], 0, 0, 0);
                acc0[nt] = __builtin_amdgcn_mfma_f32_16x16x32_bf16(al0, bh, acc0[nt], 0, 0, 0);
                acc1[nt] = __builtin_amdgcn_mfma_f32_16x16x32_bf16(ah1, bh, acc1[nt], 0, 0, 0);
                acc1[nt] = __builtin_amdgcn_mfma_f32_16x16x32_bf16(ah1, bl, acc1[nt], 0, 0, 0);
                acc1[nt] = __builtin_amdgcn_mfma_f32_16x16x32_bf16(al1, bh, acc1[nt], 0, 0, 0);
            }
        }
        float* Yo = Y1 + (size_t)ks * 802816;
        #pragma unroll
        for (int nt = 0; nt < 4; ++nt) {
            const int f = nt * 16 + l15;
            #pragma unroll
            for (int r = 0; r < 4; ++r) {
                Yo[((size_t)d * 256 + m00 + r) * 64 + f] = acc0[nt][r];
                Yo[((size_t)d * 256 + m01 + r) * 64 + f] = acc1[nt][r];
            }
        }
    }
}

// ============ sparams device fn ============
__device__ __forceinline__ void d_bilin(
    const float accy, const float accx, const int hp, const int wp,
    const int b, const int k, const int H, const int W, const int Hp, const int Wp,
    float& s_out, int& src_out)
{
    const float y = (float)(hp + (k / 7) - 3) + accy;
    const float x = (float)(wp + (k % 7) - 3) + accx;
    const float fy0 = floorf(y), fx0 = floorf(x);
    const int iy0 = (int)fy0, ix0 = (int)fx0;
    const float wy1 = y - fy0, wx1 = x - fx0;
    int ye, xe; float wy, wx;
    if (iy0 & 1) { ye = iy0 + 1; wy = wy1; } else { ye = iy0; wy = 1.f - wy1; }
    if (ix0 & 1) { xe = ix0 + 1; wx = wx1; } else { xe = ix0; wx = 1.f - wx1; }
    float s = wy * wx;
    int src = 0;
    if (ye >= 0 && ye < Hp && xe >= 0 && xe < Wp)
        src = (b * H + (ye >> 1)) * W + (xe >> 1);
    else
        s = 0.f;
    s_out = s;
    src_out = src;
}

// ============ stage-1 combine (fused sparams_z1, 4 partials) ============
__global__ __launch_bounds__(256) void k_combine1(
    const float* __restrict__ Y, const float* __restrict__ Zp,
    const float* __restrict__ OB, const float* __restrict__ bias,
    short* __restrict__ xhi, short* __restrict__ xlo)
{
    __shared__ float ss[4][49];
    __shared__ int   isrc[4][49];
    const int tid = threadIdx.x;

    if (tid < 196) {
        const int p = tid / 49, k = tid - p * 49;
        const int pixg = blockIdx.x * 4 + p;
        const int b   = pixg >> 9;
        const int rem = pixg & 511;
        const int hp  = rem >> 5;
        const int wp  = rem & 31;
        float accy = OB[2 * k], accx = OB[2 * k + 1];
        const int di0 = (hp + 1) & 1, dj0 = (wp + 1) & 1;
        for (int di = di0; di < 7; di += 2) {
            const int yp = hp + di - 3;
            if ((unsigned)yp >= 16u) continue;
            const int ys = yp >> 1;
            for (int dj = dj0; dj < 7; dj += 2) {
                const int xp = wp + dj - 3;
                if ((unsigned)xp >= 32u) continue;
                const int xs = xp >> 1;
                const size_t o = ((size_t)((di * 7 + dj) * 256 + (b * 8 + ys) * 16 + xs)) * 98 + 2 * k;
                accy += (Zp[o] + Zp[o + 1229312]) + (Zp[o + 2458624] + Zp[o + 3687936]);
                accx += (Zp[o + 1] + Zp[o + 1229313]) + (Zp[o + 2458625] + Zp[o + 3687937]);
            }
        }
        d_bilin(accy, accx, hp, wp, b, k, 8, 16, 16, 32, ss[p][k], isrc[p][k]);
    }
    __syncthreads();

    const int f = tid & 63;
    const int p = tid >> 6;
    const int pixg = blockIdx.x * 4 + p;
    float acc = bias[f];
    #pragma unroll 7
    for (int k = 0; k < K49; ++k) {
        const size_t yo = ((size_t)k * 256 + isrc[p][k]) * 64 + f;
        const float yv = (Y[yo] + Y[yo + 802816]) + (Y[yo + 1605632] + Y[yo + 2408448]);
        acc = fmaf(ss[p][k], yv, acc);
    }
    const float v = fmaxf(acc, 0.f);
    const size_t o = (size_t)pixg * 64 + f;
    const short h = f2bf(v);
    xhi[o] = h;
    xlo[o] = f2bf(v - bf2f(h));
}

// ============ stages 2-3 GEMMs merged (offmfma + ygemm23): grid (gx, 53) ====
template<int C, int F>
__global__ __launch_bounds__(256) void k_gemms23(
    const short* __restrict__ Xbf, const short* __restrict__ OWf,
    const short* __restrict__ Wf,
    float* __restrict__ off, float* __restrict__ Y,
    const int H, const int W, const int Hp, const int Wp,
    const int M, const int nX)
{
    const int tid = threadIdx.x;
    const int wv = tid >> 6;
    const int l  = tid & 63;
    const int l15 = l & 15, l4 = l >> 4;
    const int by = blockIdx.y;

    if (by < 4) {
        const int cls = by;
        const int pi = cls >> 1, rho = cls & 1;
        const int NRc = pi ? 4 : 3, NCc = rho ? 4 : 3;
        const int T = NRc * NCc;
        int nkb, clsoff;
        if (C == 64) { nkb = T * 2; clsoff = cls == 0 ? 0 : cls == 1 ? 18 : cls == 2 ? 42 : 66; }
        else         { nkb = T;     clsoff = cls == 0 ? 0 : cls == 1 ? 9  : cls == 2 ? 21 : 33; }

        const int Wt16 = W >> 4;
        const int mt = blockIdx.x * 4 + wv;
        const int rloc = mt / Wt16, xt = mt - rloc * Wt16;
        const int b = rloc / H;
        const int ysp = rloc - b * H;

        f32x4 acc[7];
        #pragma unroll
        for (int nt = 0; nt < 7; ++nt) acc[nt] = (f32x4){0.f, 0.f, 0.f, 0.f};

        const bf16x8* Bbase = (const bf16x8*)OWf + ((size_t)clsoff * 7) * 64 + l4 * 16 + l15;

        for (int kb = 0; kb < nkb; ++kb) {
            int tl, c0;
            if (C == 64) { tl = kb >> 1; c0 = ((kb & 1) << 5) + l4 * 8; }
            else         { tl = kb;      c0 = l4 * 8; }
            int iy, ix;
            if (NCc == 4) { iy = tl >> 2; ix = tl & 3; }
            else          { iy = tl / 3;  ix = tl - iy * 3; }
            const int ys = ysp + iy - 1;
            const int xs = xt * 16 + l15 + ix - 1;
            bf16x8 ah = {0, 0, 0, 0, 0, 0, 0, 0};
            bf16x8 al = {0, 0, 0, 0, 0, 0, 0, 0};
            if ((unsigned)ys < (unsigned)H && (unsigned)xs < (unsigned)W) {
                const size_t a = ((size_t)(b * H + ys) * W + xs) * C + c0;
                ah = *(const bf16x8*)(Xbf + a);
                al = *(const bf16x8*)(Xbf + nX + a);
            }
            const bf16x8* Bb = Bbase + (size_t)kb * 7 * 64;
            #pragma unroll
            for (int nt = 0; nt < 7; ++nt) {
                const bf16x8 bf = Bb[nt * 64];
                acc[nt] = __builtin_amdgcn_mfma_f32_16x16x32_bf16(ah, bf, acc[nt], 0, 0, 0);
                acc[nt] = __builtin_amdgcn_mfma_f32_16x16x32_bf16(al, bf, acc[nt], 0, 0, 0);
            }
        }

        const int hp = 2 * ysp + pi;
        const int wpbase = (xt << 5) + rho;
        const int pixrow = (b * Hp + hp) * Wp + wpbase;
        #pragma unroll
        for (int nt = 0; nt < 7; ++nt) {
            const int oc = nt * 16 + l15;
            if (oc < 98) {
                #pragma unroll
                for (int r = 0; r < 4; ++r) {
                    const int m = l4 * 4 + r;
                    off[(size_t)(pixrow + 2 * m) * 98 + oc] = acc[nt][r];
                }
            }
        }
    } else {
        constexpr int KB = C / 32;
        constexpr int NT = F / 16;
        constexpr int PLANEFRAG = 49 * NT * KB * 64;
        const int d = by - 4;
        const int mtile = blockIdx.x * 4 + wv;
        const short* Arow = Xbf + (size_t)(mtile * 16 + l15) * C + l4 * 8;

        f32x4 acc[NT];
        #pragma unroll
        for (int nt = 0; nt < NT; ++nt) acc[nt] = (f32x4){0.f, 0.f, 0.f, 0.f};

        #pragma unroll
        for (int kb = 0; kb < KB; ++kb) {
            const bf16x8 ah = *(const bf16x8*)(Arow + kb * 32);
            const bf16x8 al = *(const bf16x8*)(Arow + nX + kb * 32);
            #pragma unroll
            for (int nt = 0; nt < NT; ++nt) {
                const size_t fi = ((size_t)(d * NT + nt) * KB + kb) * 64 + l4 * 16 + l15;
                const bf16x8 bh = ((const bf16x8*)Wf)[fi];
                const bf16x8 bl = ((const bf16x8*)Wf)[fi + PLANEFRAG];
                acc[nt] = __builtin_amdgcn_mfma_f32_16x16x32_bf16(ah, bh, acc[nt], 0, 0, 0);
                acc[nt] = __builtin_amdgcn_mfma_f32_16x16x32_bf16(ah, bl, acc[nt], 0, 0, 0);
                acc[nt] = __builtin_amdgcn_mfma_f32_16x16x32_bf16(al, bh, acc[nt], 0, 0, 0);
            }
        }

        const int m0 = mtile * 16 + l4 * 4;
        #pragma unroll
        for (int nt = 0; nt < NT; ++nt) {
            const int f = nt * 16 + l15;
            #pragma unroll
            for (int r = 0; r < 4; ++r)
                Y[((size_t)d * M + m0 + r) * F + f] = acc[nt][r];
        }
    }
}

// ============ stages 2-3 combine (fused sparams, optional Y4) ============
template<int F, bool DO_Y4>
__global__ __launch_bounds__(256) void k_combine23(
    const float* __restrict__ Y, const float* __restrict__ off,
    const float* __restrict__ OB, const float* __restrict__ bias,
    short* __restrict__ xhi, short* __restrict__ xlo,
    const float* __restrict__ w4, float* __restrict__ Y4,
    const int npix, const int nsrc,
    const int H, const int W, const int Hp, const int Wp)
{
    constexpr int PPB = 256 / F;
    __shared__ float ss[PPB][49];
    __shared__ int   isrc[PPB][49];
    __shared__ float xv[DO_Y4 ? PPB : 1][DO_Y4 ? 17 : 1];
    __shared__ float w4s[DO_Y4 ? 784 : 1];
    const int tid = threadIdx.x;
    const int HWp = Hp * Wp;

    if (DO_Y4) {
        for (int t = tid; t < 784; t += 256) w4s[t] = w4[t];
    }
    for (int t = tid; t < PPB * 49; t += 256) {
        const int p = t / 49, k = t - p * 49;
        const int pixg = blockIdx.x * PPB + p;
        const float accy = OB[2 * k]     + off[(size_t)pixg * 98 + 2 * k];
        const float accx = OB[2 * k + 1] + off[(size_t)pixg * 98 + 2 * k + 1];
        const int b = pixg / HWp;
        const int rem = pixg - b * HWp;
        const int hp = rem / Wp;
        const int wp = rem - hp * Wp;
        d_bilin(accy, accx, hp, wp, b, k, H, W, Hp, Wp, ss[p][k], isrc[p][k]);
    }
    __syncthreads();

    const int f = tid % F;
    const int p2 = tid / F;
    const int pixg2 = blockIdx.x * PPB + p2;
    float acc = bias[f];
    #pragma unroll 7
    for (int k = 0; k < K49; ++k)
        acc = fmaf(ss[p2][k], Y[((size_t)k * nsrc + isrc[p2][k]) * F + f], acc);
    const float v = fmaxf(acc, 0.f);
    const size_t o = (size_t)pixg2 * F + f;
    const short h = f2bf(v);
    xhi[o] = h;
    xlo[o] = f2bf(v - bf2f(h));

    if (DO_Y4) {
        xv[p2][f] = v;
        __syncthreads();
        for (int t = tid; t < PPB * 49; t += 256) {
            const int p = t / 49, k = t - p * 49;
            float d = 0.f;
            #pragma unroll
            for (int f2 = 0; f2 < 16; ++f2)
                d = fmaf(xv[p][f2], w4s[k * 16 + f2], d);
            Y4[(size_t)k * npix + blockIdx.x * PPB + p] = d;
        }
    }
}

// ============ stage 4 FUSED: implicit-GEMM offsets (LDS) + sparams + dconv ==
// grid (256, 4); block handles 64 pixels of one parity class.
__global__ __launch_bounds__(256) void k_stage4(
    const short* __restrict__ Xbf, const short* __restrict__ OWf,
    const float* __restrict__ Y4,       // [49][nsrc]
    const float* __restrict__ OB, const float* __restrict__ bias,
    float* __restrict__ out, const int nX)
{
    constexpr int C = 16, H = 64, W = 128, Hp = 128, Wp = 256;
    __shared__ float offs[64][98];
    __shared__ float OBs[98];

    const int tid = threadIdx.x;
    const int wv = tid >> 6;
    const int l  = tid & 63;
    const int l15 = l & 15, l4 = l >> 4;
    const int cls = blockIdx.y;
    const int pi = cls >> 1, rho = cls & 1;
    const int NRc = pi ? 4 : 3, NCc = rho ? 4 : 3;
    const int T = NRc * NCc;
    const int nkb = (T + 1) >> 1;
    const int clsoff = cls == 0 ? 0 : cls == 1 ? 5 : cls == 2 ? 11 : 17;

    if (tid < 98) OBs[tid] = OB[tid];

    // ---- phase 1: implicit-GEMM MFMA, acc -> LDS ----
    const int mt = blockIdx.x * 4 + wv;
    const int rloc = mt >> 3, xt = mt & 7;     // Wt16 = 8
    const int b = rloc / H;
    const int ysp = rloc - b * H;

    f32x4 acc[7];
    #pragma unroll
    for (int nt = 0; nt < 7; ++nt) acc[nt] = (f32x4){0.f, 0.f, 0.f, 0.f};

    const bf16x8* Bbase = (const bf16x8*)OWf + ((size_t)clsoff * 7) * 64 + l4 * 16 + l15;

    for (int kb = 0; kb < nkb; ++kb) {
        int tl = kb * 2 + (l4 >> 1);
        const int c0 = (l4 & 1) * 8;
        if (tl >= T) tl = T - 1;               // B is zero there; A clamp for bounds only
        int iy, ix;
        if (NCc == 4) { iy = tl >> 2; ix = tl & 3; }
        else          { iy = tl / 3;  ix = tl - iy * 3; }
        const int ys = ysp + iy - 1;
        const int xs = xt * 16 + l15 + ix - 1;
        bf16x8 ah = {0, 0, 0, 0, 0, 0, 0, 0};
        bf16x8 al = {0, 0, 0, 0, 0, 0, 0, 0};
        if ((unsigned)ys < (unsigned)H && (unsigned)xs < (unsigned)W) {
            const size_t a = ((size_t)(b * H + ys) * W + xs) * C + c0;
            ah = *(const bf16x8*)(Xbf + a);
            al = *(const bf16x8*)(Xbf + nX + a);
        }
        const bf16x8* Bb = Bbase + (size_t)kb * 7 * 64;
        #pragma unroll
        for (int nt = 0; nt < 7; ++nt) {
            const bf16x8 bf = Bb[nt * 64];
            acc[nt] = __builtin_amdgcn_mfma_f32_16x16x32_bf16(ah, bf, acc[nt], 0, 0, 0);
            acc[nt] = __builtin_amdgcn_mfma_f32_16x16x32_bf16(al, bf, acc[nt], 0, 0, 0);
        }
    }

    #pragma unroll
    for (int nt = 0; nt < 7; ++nt) {
        const int oc = nt * 16 + l15;
        if (oc < 98) {
            #pragma unroll
            for (int r = 0; r < 4; ++r)
                offs[wv * 16 + l4 * 4 + r][oc] = acc[nt][r];
        }
    }
    __syncthreads();

    // ---- phase 2: sparams + gather-combine (4 lanes per pixel) ----
    const int p  = tid >> 2;                   // 0..63 block-local pixel
    const int tq = tid & 3;
    const int t0 = (tq == 0) ? 0 : 13 + (tq - 1) * 12;
    const int t1 = t0 + ((tq == 0) ? 13 : 12);

    const int wv_p = p >> 4;
    const int m_p  = p & 15;
    const int mt_p = blockIdx.x * 4 + wv_p;
    const int rloc_p = mt_p >> 3, xt_p = mt_p & 7;
    const int b_p = rloc_p / H;
    const int ysp_p = rloc_p - b_p * H;
    const int hp = 2 * ysp_p + pi;
    const int wp = (xt_p << 5) + rho + 2 * m_p;
    const int pixg = (b_p * Hp + hp) * Wp + wp;

    float acc2 = 0.f;
    for (int k = t0; k < t1; ++k) {
        const float offy = offs[p][2 * k]     + OBs[2 * k];
        const float offx = offs[p][2 * k + 1] + OBs[2 * k + 1];
        float s; int src;
        d_bilin(offy, offx, hp, wp, b_p, k, H, W, Hp, Wp, s, src);
        acc2 = fmaf(s, Y4[(size_t)k * 16384 + src], acc2);
    }
    acc2 += __shfl_xor(acc2, 1);
    acc2 += __shfl_xor(acc2, 2);
    if (tq == 0) out[pixg] = acc2 + bias[0];
}

extern "C" void kernel_launch(void* const* d_in, const int* in_sizes, int n_in,
                              void* d_out, int out_size, void* d_ws, size_t ws_size,
                              hipStream_t stream) {
    const float* z   = (const float*)d_in[0];
    const float* dw  = (const float*)d_in[1];
    const float* db  = (const float*)d_in[2];
    const float* ow1 = (const float*)d_in[3];
    const float* ob1 = (const float*)d_in[4];
    const float* w1  = (const float*)d_in[5];
    const float* b1  = (const float*)d_in[6];
    const float* ow2 = (const float*)d_in[7];
    const float* ob2 = (const float*)d_in[8];
    const float* w2  = (const float*)d_in[9];
    const float* b2  = (const float*)d_in[10];
    const float* ow3 = (const float*)d_in[11];
    const float* ob3 = (const float*)d_in[12];
    const float* w3  = (const float*)d_in[13];
    const float* b3  = (const float*)d_in[14];
    const float* ow4 = (const float*)d_in[15];
    const float* ob4 = (const float*)d_in[16];
    const float* w4  = (const float*)d_in[17];
    const float* b4  = (const float*)d_in[18];

    // workspace layout: ~92 MB, no aliasing (ws_size = 256 MiB)
    float* ws   = (float*)d_ws;
    short* Xf   = (short*)ws;                    // 524,288 sh
    float* Zp   = ws + 262144;                   // 4 x 1,229,312 = 4,917,248
    float* Y1   = Zp + 4917248;                  // 4 x 802,816 = 3,211,264
    float* Y2   = Y1 + 3211264;                  // 1,605,632
    float* Y3   = Y2 + 1605632;                  // 3,211,264
    float* Y4   = Y3 + 3211264;                  // 802,816
    short* Xbf1 = (short*)(Y4 + 802816);         // 131,072 sh
    short* Xbf2 = Xbf1 + 131072;                 // 262,144 sh
    short* Xbf3 = Xbf2 + 262144;                 // 524,288 sh
    float* off2 = (float*)(Xbf3 + 524288);       // 401,408
    float* off3 = off2 + 401408;                 // 1,605,632
    short* OWbf = (short*)(off3 + 1605632);      // 5,619,712 sh
    short* W1f  = OWbf + 5619712;                // 6,422,528 sh
    short* OWf2 = W1f + 6422528;                 // 351,232 sh
    short* W2f  = OWf2 + 351232;                 // 200,704 sh
    short* OWf3 = W2f + 200704;                  // 175,616 sh
    short* W3f  = OWf3 + 175616;                 // 50,176 sh
    short* OWf4 = W3f + 50176;                   // 89,600 sh

    float* out = (float*)d_out;

    // 1) dense+cvt AND all weight packing (independent, one launch)
    k_prep<<<7294, 256, 0, stream>>>(z, dw, db, Xf, ow1, w1, ow2, w2, ow3, w3, ow4,
                                     OWbf, W1f, OWf2, W2f, OWf3, W3f, OWf4);

    // 2) stage-1 GEMMs (offset + Y; K-split x4, 2-mtile B-reuse, XCD-chunked)
    k_gemms1<<<784, 256, 0, stream>>>(Xf, OWbf, W1f, Zp, Y1);

    // 3) stage-1 combine (fused sparams_z1, sums 4 partials) -> Xbf1
    k_combine1<<<256, 256, 0, stream>>>(Y1, Zp, ob1, b1, Xbf1, Xbf1 + 65536);

    // 4) stage-2 GEMMs (offmfma + ygemm, merged)
    k_gemms23<64, 32><<<dim3(16, 53), 256, 0, stream>>>(
        Xbf1, OWf2, W2f, off2, Y2, 16, 32, 32, 64, 1024, 65536);

    // 5) stage-2 combine -> Xbf2
    k_combine23<32, false><<<512, 256, 0, stream>>>(
        Y2, off2, ob2, b2, Xbf2, Xbf2 + 131072, nullptr, nullptr, 4096, 1024, 16, 32, 32, 64);

    // 6) stage-3 GEMMs
    k_gemms23<32, 16><<<dim3(64, 53), 256, 0, stream>>>(
        Xbf2, OWf3, W3f, off3, Y3, 32, 64, 64, 128, 4096, 131072);

    // 7) stage-3 combine + Y4 -> Xbf3, Y4
    k_combine23<16, true><<<1024, 256, 0, stream>>>(
        Y3, off3, ob3, b3, Xbf3, Xbf3 + 262144, w4, Y4, 16384, 4096, 32, 64, 64, 128);

    // 8) stage-4 fused: offsets (MFMA->LDS) + sparams + dconv -> out
    k_stage4<<<dim3(256, 4), 256, 0, stream>>>(Xbf3, OWf4, Y4, ob4, b4, out, 262144);
}

// Round 15
// 148.221 us; speedup vs baseline: 1.0132x; 1.0132x over previous
//
#include <hip/hip_runtime.h>
#include <hip/hip_bf16.h>

#define K49 49

typedef short bf16x8 __attribute__((ext_vector_type(8)));
typedef float f32x4 __attribute__((ext_vector_type(4)));

__device__ __forceinline__ short f2bf(float x) {
    __hip_bfloat16 h = __float2bfloat16(x);
    return __builtin_bit_cast(short, h);
}
__device__ __forceinline__ float bf2f(short s) {
    unsigned u = ((unsigned)(unsigned short)s) << 16;
    return __builtin_bit_cast(float, u);
}

// ==================== weight packing (device fns) ====================
__device__ __forceinline__ void d_pack_ow1(
    const int gid, const float* __restrict__ OW, short* __restrict__ OWbf)
{
    const int ni = gid & 15;
    int t = gid >> 4;
    const int kg = t & 3;  t >>= 2;
    const int kb = t & 31; t >>= 5;
    const int nt = t % 7;
    const int d  = t / 7;
    const int oc = nt * 16 + ni;
    short h[8];
    if (oc < 98) {
        const int c0 = kb * 32 + kg * 8;
        #pragma unroll
        for (int j = 0; j < 8; ++j)
            h[j] = f2bf(OW[((size_t)d * 1024 + c0 + j) * 98 + oc]);
    } else {
        #pragma unroll
        for (int j = 0; j < 8; ++j) h[j] = 0;
    }
    *(bf16x8*)(OWbf + (size_t)gid * 8) = *(bf16x8*)h;
}

template<int C, int F>
__device__ __forceinline__ void d_pack_w(
    const int gid, const float* __restrict__ Wt, short* __restrict__ Wf)
{
    constexpr int KB = C / 32;
    constexpr int NT = F / 16;
    constexpr int PLANE = 49 * NT * KB * 4 * 16 * 8;   // shorts
    const int ni = gid & 15;
    int t = gid >> 4;
    const int kg = t & 3; t >>= 2;
    const int kb = t % KB; t /= KB;
    const int nt = t % NT;
    const int d  = t / NT;
    const int f = nt * 16 + ni;
    const int c0 = kb * 32 + kg * 8;
    short hi[8], lo[8];
    #pragma unroll
    for (int j = 0; j < 8; ++j) {
        const float v = Wt[((size_t)d * C + c0 + j) * F + f];
        hi[j] = f2bf(v);
        lo[j] = f2bf(v - bf2f(hi[j]));
    }
    *(bf16x8*)(Wf + (size_t)gid * 8) = *(bf16x8*)hi;
    *(bf16x8*)(Wf + PLANE + (size_t)gid * 8) = *(bf16x8*)lo;
}

template<int C>
__device__ __forceinline__ void d_pack_owf(
    const int gid, const float* __restrict__ OW, short* __restrict__ OWf)
{
    const int j = gid & 7;
    int t = gid >> 3;
    const int fi = t & 63; t >>= 6;
    const int nt = t % 7;
    const int kbg = t / 7;
    const int ni = fi & 15, kg = fi >> 4;

    int cum1, cum2, cum3;
    if (C == 64)      { cum1 = 18; cum2 = 42; cum3 = 66; }
    else if (C == 32) { cum1 = 9;  cum2 = 21; cum3 = 33; }
    else              { cum1 = 5;  cum2 = 11; cum3 = 17; }
    int cls, kb0;
    if (kbg < cum1)      { cls = 0; kb0 = 0; }
    else if (kbg < cum2) { cls = 1; kb0 = cum1; }
    else if (kbg < cum3) { cls = 2; kb0 = cum2; }
    else                 { cls = 3; kb0 = cum3; }
    const int kbl = kbg - kb0;
    const int pi = cls >> 1, rho = cls & 1;
    const int NRc = pi ? 4 : 3, NCc = rho ? 4 : 3;
    const int T = NRc * NCc;

    const int k = kbl * 32 + kg * 8 + j;
    const int tl = k / C, c = k - tl * C;
    const int oc = nt * 16 + ni;
    float v = 0.f;
    if (tl < T && oc < 98) {
        const int iy = tl / NCc, ix = tl - iy * NCc;
        const int d = (1 - pi + 2 * iy) * 7 + (1 - rho + 2 * ix);
        v = OW[((size_t)d * C + c) * 98 + oc];
    }
    OWf[gid] = f2bf(v);
}

// ==================== mega prep kernel: dense+cvt AND all weight packs =====
// Xf layout (bf16): [plane(2)][mtile(16)][kb(32)][kg(4)][mi(16)][8]
__global__ __launch_bounds__(256) void k_prep(
    const float* __restrict__ z, const float* __restrict__ Wd,
    const float* __restrict__ bd, short* __restrict__ Xf,
    const float* __restrict__ ow1, const float* __restrict__ w1,
    const float* __restrict__ ow2, const float* __restrict__ w2,
    const float* __restrict__ ow3, const float* __restrict__ w3,
    const float* __restrict__ ow4,
    short* OWbf, short* W1f, short* OWf2, short* W2f,
    short* OWf3, short* W3f, short* OWf4)
{
    const int bid0 = blockIdx.x;
    const int tid = threadIdx.x;
    __shared__ float zs[256];
    if (bid0 < 512) {
        const int D = 131072;
        zs[tid] = z[tid];
        __syncthreads();
        const int n = bid0 * 256 + tid;
        const float bb = bd[n];
        float a0 = bb, a1 = bb;
        #pragma unroll 8
        for (int kk = 0; kk < 128; ++kk) {
            const float w = Wd[kk * D + n];
            a0 = fmaf(zs[kk], w, a0);
            a1 = fmaf(zs[128 + kk], w, a1);
        }
        a0 = fmaxf(a0, 0.f);
        a1 = fmaxf(a1, 0.f);
        const int c = n & 1023;
        const int m0 = n >> 10;
        const int kb = c >> 5, kg = (c >> 3) & 3, j = c & 7;
        const size_t base = ((size_t)kb * 4 + kg) * 16 * 8 + j;
        {
            const size_t dst = ((size_t)(m0 >> 4) * 2048) * 8 + base + (size_t)(m0 & 15) * 8;
            const short h = f2bf(a0);
            Xf[dst] = h;
            Xf[262144 + dst] = f2bf(a0 - bf2f(h));
        }
        {
            const int m1 = m0 + 128;
            const size_t dst = ((size_t)(m1 >> 4) * 2048) * 8 + base + (size_t)(m1 & 15) * 8;
            const short h = f2bf(a1);
            Xf[dst] = h;
            Xf[262144 + dst] = f2bf(a1 - bf2f(h));
        }
        return;
    }
    const int bid = bid0 - 512;
    if (bid < 2744)      d_pack_ow1((bid) * 256 + tid, ow1, OWbf);
    else if (bid < 4312) d_pack_w<1024, 64>((bid - 2744) * 256 + tid, w1, W1f);
    else if (bid < 5684) d_pack_owf<64>((bid - 4312) * 256 + tid, ow2, OWf2);
    else if (bid < 5733) d_pack_w<64, 32>((bid - 5684) * 256 + tid, w2, W2f);
    else if (bid < 6419) d_pack_owf<32>((bid - 5733) * 256 + tid, ow3, OWf3);
    else if (bid < 6432) { const int g = (bid - 6419) * 256 + tid; if (g < 3136) d_pack_w<32, 16>(g, w3, W3f); }
    else                 d_pack_owf<16>((bid - 6432) * 256 + tid, ow4, OWf4);
}

// ============ stage-1 GEMMs, K-split x4 + N-split x2: grid 3136 =====
// Zp partial: [ks][49][256][98]; Y1 partial: [ks][49][256][64]
// work = (ks*196 + by)*4 + x; by<98: Z (d=by/2, nt-half), else Y (2 nt-half)
__global__ __launch_bounds__(256) void k_gemms1(
    const short* __restrict__ Xf, const short* __restrict__ OWbf,
    const short* __restrict__ W1f,
    float* __restrict__ Zp, float* __restrict__ Y1)
{
    const int tid = threadIdx.x;
    const int wv = tid >> 6;
    const int l  = tid & 63;
    const int l15 = l & 15, l4 = l >> 4;

    // XCD-aware: 4 M-sibling blocks (same B-slice) consecutive -> same XCD
    const int bid = blockIdx.x;                  // 0..3135
    const int work = (bid & 7) * 392 + (bid >> 3);
    const int x    = work & 3;
    const int rest = work >> 2;                  // 0..783
    const int ks   = rest / 196;
    const int by   = rest - ks * 196;

    const int mtile = x * 4 + wv;
    const int kb0 = ks * 8;
    const int lofs = l4 * 16 + l15;

    const bf16x8* Ah = (const bf16x8*)Xf + (size_t)mtile * 2048 + lofs;
    const bf16x8* Al = Ah + 32768;
    const int m0 = mtile * 16 + l4 * 4;

    if (by < 98) {
        const int d   = by >> 1;
        const int nth = by & 1;
        const int nt0 = nth * 4;
        const int NT  = nth ? 3 : 4;
        const bf16x8* Bb = (const bf16x8*)OWbf + (size_t)(d * 7 + nt0) * 2048 + lofs;
        f32x4 acc[4];
        #pragma unroll
        for (int nt = 0; nt < 4; ++nt) acc[nt] = (f32x4){0.f, 0.f, 0.f, 0.f};
        #pragma unroll
        for (int i = 0; i < 8; ++i) {
            const int kb = kb0 + i;
            const bf16x8 ah = Ah[kb * 64];
            const bf16x8 al = Al[kb * 64];
            for (int nt = 0; nt < NT; ++nt) {
                const bf16x8 b = Bb[(size_t)nt * 2048 + kb * 64];
                acc[nt] = __builtin_amdgcn_mfma_f32_16x16x32_bf16(ah, b, acc[nt], 0, 0, 0);
                acc[nt] = __builtin_amdgcn_mfma_f32_16x16x32_bf16(al, b, acc[nt], 0, 0, 0);
            }
        }
        float* Zo = Zp + (size_t)ks * 1229312;
        for (int nt = 0; nt < NT; ++nt) {
            const int oc = (nt0 + nt) * 16 + l15;
            if (oc < 98) {
                #pragma unroll
                for (int r = 0; r < 4; ++r)
                    Zo[((size_t)d * 256 + m0 + r) * 98 + oc] = acc[nt][r];
            }
        }
    } else {
        const int dd  = by - 98;
        const int d   = dd >> 1;
        const int nt0 = (dd & 1) * 2;
        const bf16x8* Bh = (const bf16x8*)W1f + (size_t)(d * 4 + nt0) * 2048 + lofs;
        const bf16x8* Bl = Bh + 401408;
        f32x4 acc[2];
        #pragma unroll
        for (int nt = 0; nt < 2; ++nt) acc[nt] = (f32x4){0.f, 0.f, 0.f, 0.f};
        #pragma unroll
        for (int i = 0; i < 8; ++i) {
            const int kb = kb0 + i;
            const bf16x8 ah = Ah[kb * 64];
            const bf16x8 al = Al[kb * 64];
            #pragma unroll
            for (int nt = 0; nt < 2; ++nt) {
                const bf16x8 bh = Bh[nt * 2048 + kb * 64];
                const bf16x8 bl = Bl[nt * 2048 + kb * 64];
                acc[nt] = __builtin_amdgcn_mfma_f32_16x16x32_bf16(ah, bh, acc[nt], 0, 0, 0);
                acc[nt] = __builtin_amdgcn_mfma_f32_16x16x32_bf16(ah, bl, acc[nt], 0, 0, 0);
                acc[nt] = __builtin_amdgcn_mfma_f32_16x16x32_bf16(al, bh, acc[nt], 0, 0, 0);
            }
        }
        float* Yo = Y1 + (size_t)ks * 802816;
        #pragma unroll
        for (int nt = 0; nt < 2; ++nt) {
            const int f = (nt0 + nt) * 16 + l15;
            #pragma unroll
            for (int r = 0; r < 4; ++r)
                Yo[((size_t)d * 256 + m0 + r) * 64 + f] = acc[nt][r];
        }
    }
}

// ============ sparams device fn ============
__device__ __forceinline__ void d_bilin(
    const float accy, const float accx, const int hp, const int wp,
    const int b, const int k, const int H, const int W, const int Hp, const int Wp,
    float& s_out, int& src_out)
{
    const float y = (float)(hp + (k / 7) - 3) + accy;
    const float x = (float)(wp + (k % 7) - 3) + accx;
    const float fy0 = floorf(y), fx0 = floorf(x);
    const int iy0 = (int)fy0, ix0 = (int)fx0;
    const float wy1 = y - fy0, wx1 = x - fx0;
    int ye, xe; float wy, wx;
    if (iy0 & 1) { ye = iy0 + 1; wy = wy1; } else { ye = iy0; wy = 1.f - wy1; }
    if (ix0 & 1) { xe = ix0 + 1; wx = wx1; } else { xe = ix0; wx = 1.f - wx1; }
    float s = wy * wx;
    int src = 0;
    if (ye >= 0 && ye < Hp && xe >= 0 && xe < Wp)
        src = (b * H + (ye >> 1)) * W + (xe >> 1);
    else
        s = 0.f;
    s_out = s;
    src_out = src;
}

// ============ stage-1 combine (fused sparams_z1, 4 partials) ============
__global__ __launch_bounds__(256) void k_combine1(
    const float* __restrict__ Y, const float* __restrict__ Zp,
    const float* __restrict__ OB, const float* __restrict__ bias,
    short* __restrict__ xhi, short* __restrict__ xlo)
{
    __shared__ float ss[4][49];
    __shared__ int   isrc[4][49];
    const int tid = threadIdx.x;

    if (tid < 196) {
        const int p = tid / 49, k = tid - p * 49;
        const int pixg = blockIdx.x * 4 + p;
        const int b   = pixg >> 9;
        const int rem = pixg & 511;
        const int hp  = rem >> 5;
        const int wp  = rem & 31;
        float accy = OB[2 * k], accx = OB[2 * k + 1];
        const int di0 = (hp + 1) & 1, dj0 = (wp + 1) & 1;
        for (int di = di0; di < 7; di += 2) {
            const int yp = hp + di - 3;
            if ((unsigned)yp >= 16u) continue;
            const int ys = yp >> 1;
            for (int dj = dj0; dj < 7; dj += 2) {
                const int xp = wp + dj - 3;
                if ((unsigned)xp >= 32u) continue;
                const int xs = xp >> 1;
                const size_t o = ((size_t)((di * 7 + dj) * 256 + (b * 8 + ys) * 16 + xs)) * 98 + 2 * k;
                accy += (Zp[o] + Zp[o + 1229312]) + (Zp[o + 2458624] + Zp[o + 3687936]);
                accx += (Zp[o + 1] + Zp[o + 1229313]) + (Zp[o + 2458625] + Zp[o + 3687937]);
            }
        }
        d_bilin(accy, accx, hp, wp, b, k, 8, 16, 16, 32, ss[p][k], isrc[p][k]);
    }
    __syncthreads();

    const int f = tid & 63;
    const int p = tid >> 6;
    const int pixg = blockIdx.x * 4 + p;
    float acc = bias[f];
    #pragma unroll 7
    for (int k = 0; k < K49; ++k) {
        const size_t yo = ((size_t)k * 256 + isrc[p][k]) * 64 + f;
        const float yv = (Y[yo] + Y[yo + 802816]) + (Y[yo + 1605632] + Y[yo + 2408448]);
        acc = fmaf(ss[p][k], yv, acc);
    }
    const float v = fmaxf(acc, 0.f);
    const size_t o = (size_t)pixg * 64 + f;
    const short h = f2bf(v);
    xhi[o] = h;
    xlo[o] = f2bf(v - bf2f(h));
}

// ============ stages 2-3 GEMMs merged (offmfma + ygemm23): grid (gx, 53) ====
template<int C, int F>
__global__ __launch_bounds__(256) void k_gemms23(
    const short* __restrict__ Xbf, const short* __restrict__ OWf,
    const short* __restrict__ Wf,
    float* __restrict__ off, float* __restrict__ Y,
    const int H, const int W, const int Hp, const int Wp,
    const int M, const int nX)
{
    const int tid = threadIdx.x;
    const int wv = tid >> 6;
    const int l  = tid & 63;
    const int l15 = l & 15, l4 = l >> 4;
    const int by = blockIdx.y;

    if (by < 4) {
        const int cls = by;
        const int pi = cls >> 1, rho = cls & 1;
        const int NRc = pi ? 4 : 3, NCc = rho ? 4 : 3;
        const int T = NRc * NCc;
        int nkb, clsoff;
        if (C == 64) { nkb = T * 2; clsoff = cls == 0 ? 0 : cls == 1 ? 18 : cls == 2 ? 42 : 66; }
        else         { nkb = T;     clsoff = cls == 0 ? 0 : cls == 1 ? 9  : cls == 2 ? 21 : 33; }

        const int Wt16 = W >> 4;
        const int mt = blockIdx.x * 4 + wv;
        const int rloc = mt / Wt16, xt = mt - rloc * Wt16;
        const int b = rloc / H;
        const int ysp = rloc - b * H;

        f32x4 acc[7];
        #pragma unroll
        for (int nt = 0; nt < 7; ++nt) acc[nt] = (f32x4){0.f, 0.f, 0.f, 0.f};

        const bf16x8* Bbase = (const bf16x8*)OWf + ((size_t)clsoff * 7) * 64 + l4 * 16 + l15;

        for (int kb = 0; kb < nkb; ++kb) {
            int tl, c0;
            if (C == 64) { tl = kb >> 1; c0 = ((kb & 1) << 5) + l4 * 8; }
            else         { tl = kb;      c0 = l4 * 8; }
            int iy, ix;
            if (NCc == 4) { iy = tl >> 2; ix = tl & 3; }
            else          { iy = tl / 3;  ix = tl - iy * 3; }
            const int ys = ysp + iy - 1;
            const int xs = xt * 16 + l15 + ix - 1;
            bf16x8 ah = {0, 0, 0, 0, 0, 0, 0, 0};
            bf16x8 al = {0, 0, 0, 0, 0, 0, 0, 0};
            if ((unsigned)ys < (unsigned)H && (unsigned)xs < (unsigned)W) {
                const size_t a = ((size_t)(b * H + ys) * W + xs) * C + c0;
                ah = *(const bf16x8*)(Xbf + a);
                al = *(const bf16x8*)(Xbf + nX + a);
            }
            const bf16x8* Bb = Bbase + (size_t)kb * 7 * 64;
            #pragma unroll
            for (int nt = 0; nt < 7; ++nt) {
                const bf16x8 bf = Bb[nt * 64];
                acc[nt] = __builtin_amdgcn_mfma_f32_16x16x32_bf16(ah, bf, acc[nt], 0, 0, 0);
                acc[nt] = __builtin_amdgcn_mfma_f32_16x16x32_bf16(al, bf, acc[nt], 0, 0, 0);
            }
        }

        const int hp = 2 * ysp + pi;
        const int wpbase = (xt << 5) + rho;
        const int pixrow = (b * Hp + hp) * Wp + wpbase;
        #pragma unroll
        for (int nt = 0; nt < 7; ++nt) {
            const int oc = nt * 16 + l15;
            if (oc < 98) {
                #pragma unroll
                for (int r = 0; r < 4; ++r) {
                    const int m = l4 * 4 + r;
                    off[(size_t)(pixrow + 2 * m) * 98 + oc] = acc[nt][r];
                }
            }
        }
    } else {
        constexpr int KB = C / 32;
        constexpr int NT = F / 16;
        constexpr int PLANEFRAG = 49 * NT * KB * 64;
        const int d = by - 4;
        const int mtile = blockIdx.x * 4 + wv;
        const short* Arow = Xbf + (size_t)(mtile * 16 + l15) * C + l4 * 8;

        f32x4 acc[NT];
        #pragma unroll
        for (int nt = 0; nt < NT; ++nt) acc[nt] = (f32x4){0.f, 0.f, 0.f, 0.f};

        #pragma unroll
        for (int kb = 0; kb < KB; ++kb) {
            const bf16x8 ah = *(const bf16x8*)(Arow + kb * 32);
            const bf16x8 al = *(const bf16x8*)(Arow + nX + kb * 32);
            #pragma unroll
            for (int nt = 0; nt < NT; ++nt) {
                const size_t fi = ((size_t)(d * NT + nt) * KB + kb) * 64 + l4 * 16 + l15;
                const bf16x8 bh = ((const bf16x8*)Wf)[fi];
                const bf16x8 bl = ((const bf16x8*)Wf)[fi + PLANEFRAG];
                acc[nt] = __builtin_amdgcn_mfma_f32_16x16x32_bf16(ah, bh, acc[nt], 0, 0, 0);
                acc[nt] = __builtin_amdgcn_mfma_f32_16x16x32_bf16(ah, bl, acc[nt], 0, 0, 0);
                acc[nt] = __builtin_amdgcn_mfma_f32_16x16x32_bf16(al, bh, acc[nt], 0, 0, 0);
            }
        }

        const int m0 = mtile * 16 + l4 * 4;
        #pragma unroll
        for (int nt = 0; nt < NT; ++nt) {
            const int f = nt * 16 + l15;
            #pragma unroll
            for (int r = 0; r < 4; ++r)
                Y[((size_t)d * M + m0 + r) * F + f] = acc[nt][r];
        }
    }
}

// ============ stages 2-3 combine (fused sparams, optional Y4) ============
template<int F, bool DO_Y4>
__global__ __launch_bounds__(256) void k_combine23(
    const float* __restrict__ Y, const float* __restrict__ off,
    const float* __restrict__ OB, const float* __restrict__ bias,
    short* __restrict__ xhi, short* __restrict__ xlo,
    const float* __restrict__ w4, float* __restrict__ Y4,
    const int npix, const int nsrc,
    const int H, const int W, const int Hp, const int Wp)
{
    constexpr int PPB = 256 / F;
    __shared__ float ss[PPB][49];
    __shared__ int   isrc[PPB][49];
    __shared__ float xv[DO_Y4 ? PPB : 1][DO_Y4 ? 17 : 1];
    __shared__ float w4s[DO_Y4 ? 784 : 1];
    const int tid = threadIdx.x;
    const int HWp = Hp * Wp;

    if (DO_Y4) {
        for (int t = tid; t < 784; t += 256) w4s[t] = w4[t];
    }
    for (int t = tid; t < PPB * 49; t += 256) {
        const int p = t / 49, k = t - p * 49;
        const int pixg = blockIdx.x * PPB + p;
        const float accy = OB[2 * k]     + off[(size_t)pixg * 98 + 2 * k];
        const float accx = OB[2 * k + 1] + off[(size_t)pixg * 98 + 2 * k + 1];
        const int b = pixg / HWp;
        const int rem = pixg - b * HWp;
        const int hp = rem / Wp;
        const int wp = rem - hp * Wp;
        d_bilin(accy, accx, hp, wp, b, k, H, W, Hp, Wp, ss[p][k], isrc[p][k]);
    }
    __syncthreads();

    const int f = tid % F;
    const int p2 = tid / F;
    const int pixg2 = blockIdx.x * PPB + p2;
    float acc = bias[f];
    #pragma unroll 7
    for (int k = 0; k < K49; ++k)
        acc = fmaf(ss[p2][k], Y[((size_t)k * nsrc + isrc[p2][k]) * F + f], acc);
    const float v = fmaxf(acc, 0.f);
    const size_t o = (size_t)pixg2 * F + f;
    const short h = f2bf(v);
    xhi[o] = h;
    xlo[o] = f2bf(v - bf2f(h));

    if (DO_Y4) {
        xv[p2][f] = v;
        __syncthreads();
        for (int t = tid; t < PPB * 49; t += 256) {
            const int p = t / 49, k = t - p * 49;
            float d = 0.f;
            #pragma unroll
            for (int f2 = 0; f2 < 16; ++f2)
                d = fmaf(xv[p][f2], w4s[k * 16 + f2], d);
            Y4[(size_t)k * npix + blockIdx.x * PPB + p] = d;
        }
    }
}

// ============ stage 4 FUSED: implicit-GEMM offsets (LDS) + sparams + dconv ==
// grid (256, 4); block handles 64 pixels of one parity class.
__global__ __launch_bounds__(256) void k_stage4(
    const short* __restrict__ Xbf, const short* __restrict__ OWf,
    const float* __restrict__ Y4,       // [49][nsrc]
    const float* __restrict__ OB, const float* __restrict__ bias,
    float* __restrict__ out, const int nX)
{
    constexpr int C = 16, H = 64, W = 128, Hp = 128, Wp = 256;
    __shared__ float offs[64][98];
    __shared__ float OBs[98];

    const int tid = threadIdx.x;
    const int wv = tid >> 6;
    const int l  = tid & 63;
    const int l15 = l & 15, l4 = l >> 4;
    const int cls = blockIdx.y;
    const int pi = cls >> 1, rho = cls & 1;
    const int NRc = pi ? 4 : 3, NCc = rho ? 4 : 3;
    const int T = NRc * NCc;
    const int nkb = (T + 1) >> 1;
    const int clsoff = cls == 0 ? 0 : cls == 1 ? 5 : cls == 2 ? 11 : 17;

    if (tid < 98) OBs[tid] = OB[tid];

    // ---- phase 1: implicit-GEMM MFMA, acc -> LDS ----
    const int mt = blockIdx.x * 4 + wv;
    const int rloc = mt >> 3, xt = mt & 7;     // Wt16 = 8
    const int b = rloc / H;
    const int ysp = rloc - b * H;

    f32x4 acc[7];
    #pragma unroll
    for (int nt = 0; nt < 7; ++nt) acc[nt] = (f32x4){0.f, 0.f, 0.f, 0.f};

    const bf16x8* Bbase = (const bf16x8*)OWf + ((size_t)clsoff * 7) * 64 + l4 * 16 + l15;

    for (int kb = 0; kb < nkb; ++kb) {
        int tl = kb * 2 + (l4 >> 1);
        const int c0 = (l4 & 1) * 8;
        if (tl >= T) tl = T - 1;               // B is zero there; A clamp for bounds only
        int iy, ix;
        if (NCc == 4) { iy = tl >> 2; ix = tl & 3; }
        else          { iy = tl / 3;  ix = tl - iy * 3; }
        const int ys = ysp + iy - 1;
        const int xs = xt * 16 + l15 + ix - 1;
        bf16x8 ah = {0, 0, 0, 0, 0, 0, 0, 0};
        bf16x8 al = {0, 0, 0, 0, 0, 0, 0, 0};
        if ((unsigned)ys < (unsigned)H && (unsigned)xs < (unsigned)W) {
            const size_t a = ((size_t)(b * H + ys) * W + xs) * C + c0;
            ah = *(const bf16x8*)(Xbf + a);
            al = *(const bf16x8*)(Xbf + nX + a);
        }
        const bf16x8* Bb = Bbase + (size_t)kb * 7 * 64;
        #pragma unroll
        for (int nt = 0; nt < 7; ++nt) {
            const bf16x8 bf = Bb[nt * 64];
            acc[nt] = __builtin_amdgcn_mfma_f32_16x16x32_bf16(ah, bf, acc[nt], 0, 0, 0);
            acc[nt] = __builtin_amdgcn_mfma_f32_16x16x32_bf16(al, bf, acc[nt], 0, 0, 0);
        }
    }

    #pragma unroll
    for (int nt = 0; nt < 7; ++nt) {
        const int oc = nt * 16 + l15;
        if (oc < 98) {
            #pragma unroll
            for (int r = 0; r < 4; ++r)
                offs[wv * 16 + l4 * 4 + r][oc] = acc[nt][r];
        }
    }
    __syncthreads();

    // ---- phase 2: sparams + gather-combine (4 lanes per pixel) ----
    const int p  = tid >> 2;                   // 0..63 block-local pixel
    const int tq = tid & 3;
    const int t0 = (tq == 0) ? 0 : 13 + (tq - 1) * 12;
    const int t1 = t0 + ((tq == 0) ? 13 : 12);

    const int wv_p = p >> 4;
    const int m_p  = p & 15;
    const int mt_p = blockIdx.x * 4 + wv_p;
    const int rloc_p = mt_p >> 3, xt_p = mt_p & 7;
    const int b_p = rloc_p / H;
    const int ysp_p = rloc_p - b_p * H;
    const int hp = 2 * ysp_p + pi;
    const int wp = (xt_p << 5) + rho + 2 * m_p;
    const int pixg = (b_p * Hp + hp) * Wp + wp;

    float acc2 = 0.f;
    for (int k = t0; k < t1; ++k) {
        const float offy = offs[p][2 * k]     + OBs[2 * k];
        const float offx = offs[p][2 * k + 1] + OBs[2 * k + 1];
        float s; int src;
        d_bilin(offy, offx, hp, wp, b_p, k, H, W, Hp, Wp, s, src);
        acc2 = fmaf(s, Y4[(size_t)k * 16384 + src], acc2);
    }
    acc2 += __shfl_xor(acc2, 1);
    acc2 += __shfl_xor(acc2, 2);
    if (tq == 0) out[pixg] = acc2 + bias[0];
}

extern "C" void kernel_launch(void* const* d_in, const int* in_sizes, int n_in,
                              void* d_out, int out_size, void* d_ws, size_t ws_size,
                              hipStream_t stream) {
    const float* z   = (const float*)d_in[0];
    const float* dw  = (const float*)d_in[1];
    const float* db  = (const float*)d_in[2];
    const float* ow1 = (const float*)d_in[3];
    const float* ob1 = (const float*)d_in[4];
    const float* w1  = (const float*)d_in[5];
    const float* b1  = (const float*)d_in[6];
    const float* ow2 = (const float*)d_in[7];
    const float* ob2 = (const float*)d_in[8];
    const float* w2  = (const float*)d_in[9];
    const float* b2  = (const float*)d_in[10];
    const float* ow3 = (const float*)d_in[11];
    const float* ob3 = (const float*)d_in[12];
    const float* w3  = (const float*)d_in[13];
    const float* b3  = (const float*)d_in[14];
    const float* ow4 = (const float*)d_in[15];
    const float* ob4 = (const float*)d_in[16];
    const float* w4  = (const float*)d_in[17];
    const float* b4  = (const float*)d_in[18];

    // workspace layout: ~92 MB, no aliasing (ws_size = 256 MiB)
    float* ws   = (float*)d_ws;
    short* Xf   = (short*)ws;                    // 524,288 sh
    float* Zp   = ws + 262144;                   // 4 x 1,229,312 = 4,917,248
    float* Y1   = Zp + 4917248;                  // 4 x 802,816 = 3,211,264
    float* Y2   = Y1 + 3211264;                  // 1,605,632
    float* Y3   = Y2 + 1605632;                  // 3,211,264
    float* Y4   = Y3 + 3211264;                  // 802,816
    short* Xbf1 = (short*)(Y4 + 802816);         // 131,072 sh
    short* Xbf2 = Xbf1 + 131072;                 // 262,144 sh
    short* Xbf3 = Xbf2 + 262144;                 // 524,288 sh
    float* off2 = (float*)(Xbf3 + 524288);       // 401,408
    float* off3 = off2 + 401408;                 // 1,605,632
    short* OWbf = (short*)(off3 + 1605632);      // 5,619,712 sh
    short* W1f  = OWbf + 5619712;                // 6,422,528 sh
    short* OWf2 = W1f + 6422528;                 // 351,232 sh
    short* W2f  = OWf2 + 351232;                 // 200,704 sh
    short* OWf3 = W2f + 200704;                  // 175,616 sh
    short* W3f  = OWf3 + 175616;                 // 50,176 sh
    short* OWf4 = W3f + 50176;                   // 89,600 sh

    float* out = (float*)d_out;

    // 1) dense+cvt AND all weight packing (independent, one launch)
    k_prep<<<7294, 256, 0, stream>>>(z, dw, db, Xf, ow1, w1, ow2, w2, ow3, w3, ow4,
                                     OWbf, W1f, OWf2, W2f, OWf3, W3f, OWf4);

    // 2) stage-1 GEMMs (offset + Y; K-split x4, N-split x2, XCD-chunked)
    k_gemms1<<<3136, 256, 0, stream>>>(Xf, OWbf, W1f, Zp, Y1);

    // 3) stage-1 combine (fused sparams_z1, sums 4 partials) -> Xbf1
    k_combine1<<<256, 256, 0, stream>>>(Y1, Zp, ob1, b1, Xbf1, Xbf1 + 65536);

    // 4) stage-2 GEMMs (offmfma + ygemm, merged)
    k_gemms23<64, 32><<<dim3(16, 53), 256, 0, stream>>>(
        Xbf1, OWf2, W2f, off2, Y2, 16, 32, 32, 64, 1024, 65536);

    // 5) stage-2 combine -> Xbf2
    k_combine23<32, false><<<512, 256, 0, stream>>>(
        Y2, off2, ob2, b2, Xbf2, Xbf2 + 131072, nullptr, nullptr, 4096, 1024, 16, 32, 32, 64);

    // 6) stage-3 GEMMs
    k_gemms23<32, 16><<<dim3(64, 53), 256, 0, stream>>>(
        Xbf2, OWf3, W3f, off3, Y3, 32, 64, 64, 128, 4096, 131072);

    // 7) stage-3 combine + Y4 -> Xbf3, Y4
    k_combine23<16, true><<<1024, 256, 0, stream>>>(
        Y3, off3, ob3, b3, Xbf3, Xbf3 + 262144, w4, Y4, 16384, 4096, 32, 64, 64, 128);

    // 8) stage-4 fused: offsets (MFMA->LDS) + sparams + dconv -> out
    k_stage4<<<dim3(256, 4), 256, 0, stream>>>(Xbf3, OWf4, Y4, ob4, b4, out, 262144);
}

// Round 16
// 137.754 us; speedup vs baseline: 1.0902x; 1.0760x over previous
//
#include <hip/hip_runtime.h>
#include <hip/hip_bf16.h>

#define K49 49

typedef short bf16x8 __attribute__((ext_vector_type(8)));
typedef float f32x4 __attribute__((ext_vector_type(4)));

__device__ __forceinline__ short f2bf(float x) {
    __hip_bfloat16 h = __float2bfloat16(x);
    return __builtin_bit_cast(short, h);
}
__device__ __forceinline__ float bf2f(short s) {
    unsigned u = ((unsigned)(unsigned short)s) << 16;
    return __builtin_bit_cast(float, u);
}

// ==================== weight packing (device fns) ====================
__device__ __forceinline__ void d_pack_ow1(
    const int gid, const float* __restrict__ OW, short* __restrict__ OWbf)
{
    const int ni = gid & 15;
    int t = gid >> 4;
    const int kg = t & 3;  t >>= 2;
    const int kb = t & 31; t >>= 5;
    const int nt = t % 7;
    const int d  = t / 7;
    const int oc = nt * 16 + ni;
    short h[8];
    if (oc < 98) {
        const int c0 = kb * 32 + kg * 8;
        #pragma unroll
        for (int j = 0; j < 8; ++j)
            h[j] = f2bf(OW[((size_t)d * 1024 + c0 + j) * 98 + oc]);
    } else {
        #pragma unroll
        for (int j = 0; j < 8; ++j) h[j] = 0;
    }
    *(bf16x8*)(OWbf + (size_t)gid * 8) = *(bf16x8*)h;
}

template<int C, int F>
__device__ __forceinline__ void d_pack_w(
    const int gid, const float* __restrict__ Wt, short* __restrict__ Wf)
{
    constexpr int KB = C / 32;
    constexpr int NT = F / 16;
    constexpr int PLANE = 49 * NT * KB * 4 * 16 * 8;   // shorts
    const int ni = gid & 15;
    int t = gid >> 4;
    const int kg = t & 3; t >>= 2;
    const int kb = t % KB; t /= KB;
    const int nt = t % NT;
    const int d  = t / NT;
    const int f = nt * 16 + ni;
    const int c0 = kb * 32 + kg * 8;
    short hi[8], lo[8];
    #pragma unroll
    for (int j = 0; j < 8; ++j) {
        const float v = Wt[((size_t)d * C + c0 + j) * F + f];
        hi[j] = f2bf(v);
        lo[j] = f2bf(v - bf2f(hi[j]));
    }
    *(bf16x8*)(Wf + (size_t)gid * 8) = *(bf16x8*)hi;
    *(bf16x8*)(Wf + PLANE + (size_t)gid * 8) = *(bf16x8*)lo;
}

template<int C>
__device__ __forceinline__ void d_pack_owf(
    const int gid, const float* __restrict__ OW, short* __restrict__ OWf)
{
    const int j = gid & 7;
    int t = gid >> 3;
    const int fi = t & 63; t >>= 6;
    const int nt = t % 7;
    const int kbg = t / 7;
    const int ni = fi & 15, kg = fi >> 4;

    int cum1, cum2, cum3;
    if (C == 64)      { cum1 = 18; cum2 = 42; cum3 = 66; }
    else if (C == 32) { cum1 = 9;  cum2 = 21; cum3 = 33; }
    else              { cum1 = 5;  cum2 = 11; cum3 = 17; }
    int cls, kb0;
    if (kbg < cum1)      { cls = 0; kb0 = 0; }
    else if (kbg < cum2) { cls = 1; kb0 = cum1; }
    else if (kbg < cum3) { cls = 2; kb0 = cum2; }
    else                 { cls = 3; kb0 = cum3; }
    const int kbl = kbg - kb0;
    const int pi = cls >> 1, rho = cls & 1;
    const int NRc = pi ? 4 : 3, NCc = rho ? 4 : 3;
    const int T = NRc * NCc;

    const int k = kbl * 32 + kg * 8 + j;
    const int tl = k / C, c = k - tl * C;
    const int oc = nt * 16 + ni;
    float v = 0.f;
    if (tl < T && oc < 98) {
        const int iy = tl / NCc, ix = tl - iy * NCc;
        const int d = (1 - pi + 2 * iy) * 7 + (1 - rho + 2 * ix);
        v = OW[((size_t)d * C + c) * 98 + oc];
    }
    OWf[gid] = f2bf(v);
}

// ==================== mega prep kernel: dense+cvt AND all weight packs =====
// Xf layout (bf16): [plane(2)][mtile(16)][kb(32)][kg(4)][mi(16)][8]
__global__ __launch_bounds__(256) void k_prep(
    const float* __restrict__ z, const float* __restrict__ Wd,
    const float* __restrict__ bd, short* __restrict__ Xf,
    const float* __restrict__ ow1, const float* __restrict__ w1,
    const float* __restrict__ ow2, const float* __restrict__ w2,
    const float* __restrict__ ow3, const float* __restrict__ w3,
    const float* __restrict__ ow4,
    short* OWbf, short* W1f, short* OWf2, short* W2f,
    short* OWf3, short* W3f, short* OWf4)
{
    const int bid0 = blockIdx.x;
    const int tid = threadIdx.x;
    __shared__ float zs[256];
    if (bid0 < 512) {
        const int D = 131072;
        zs[tid] = z[tid];
        __syncthreads();
        const int n = bid0 * 256 + tid;
        const float bb = bd[n];
        float a0 = bb, a1 = bb;
        #pragma unroll 8
        for (int kk = 0; kk < 128; ++kk) {
            const float w = Wd[kk * D + n];
            a0 = fmaf(zs[kk], w, a0);
            a1 = fmaf(zs[128 + kk], w, a1);
        }
        a0 = fmaxf(a0, 0.f);
        a1 = fmaxf(a1, 0.f);
        const int c = n & 1023;
        const int m0 = n >> 10;
        const int kb = c >> 5, kg = (c >> 3) & 3, j = c & 7;
        const size_t base = ((size_t)kb * 4 + kg) * 16 * 8 + j;
        {
            const size_t dst = ((size_t)(m0 >> 4) * 2048) * 8 + base + (size_t)(m0 & 15) * 8;
            const short h = f2bf(a0);
            Xf[dst] = h;
            Xf[262144 + dst] = f2bf(a0 - bf2f(h));
        }
        {
            const int m1 = m0 + 128;
            const size_t dst = ((size_t)(m1 >> 4) * 2048) * 8 + base + (size_t)(m1 & 15) * 8;
            const short h = f2bf(a1);
            Xf[dst] = h;
            Xf[262144 + dst] = f2bf(a1 - bf2f(h));
        }
        return;
    }
    const int bid = bid0 - 512;
    if (bid < 2744)      d_pack_ow1((bid) * 256 + tid, ow1, OWbf);
    else if (bid < 4312) d_pack_w<1024, 64>((bid - 2744) * 256 + tid, w1, W1f);
    else if (bid < 5684) d_pack_owf<64>((bid - 4312) * 256 + tid, ow2, OWf2);
    else if (bid < 5733) d_pack_w<64, 32>((bid - 5684) * 256 + tid, w2, W2f);
    else if (bid < 6419) d_pack_owf<32>((bid - 5733) * 256 + tid, ow3, OWf3);
    else if (bid < 6432) { const int g = (bid - 6419) * 256 + tid; if (g < 3136) d_pack_w<32, 16>(g, w3, W3f); }
    else                 d_pack_owf<16>((bid - 6432) * 256 + tid, ow4, OWf4);
}

// ============ Z-branch body, compile-time NT so everything unrolls =========
template<int NT>
__device__ __forceinline__ void d_zpart(
    const bf16x8* __restrict__ Ah, const bf16x8* __restrict__ Al,
    const bf16x8* __restrict__ Bb, float* __restrict__ Zo,
    const int d, const int m0, const int l15, const int nt0, const int kb0)
{
    f32x4 acc[NT];
    #pragma unroll
    for (int nt = 0; nt < NT; ++nt) acc[nt] = (f32x4){0.f, 0.f, 0.f, 0.f};
    #pragma unroll
    for (int i = 0; i < 8; ++i) {
        const int kb = kb0 + i;
        const bf16x8 ah = Ah[kb * 64];
        const bf16x8 al = Al[kb * 64];
        #pragma unroll
        for (int nt = 0; nt < NT; ++nt) {
            const bf16x8 b = Bb[(size_t)nt * 2048 + kb * 64];
            acc[nt] = __builtin_amdgcn_mfma_f32_16x16x32_bf16(ah, b, acc[nt], 0, 0, 0);
            acc[nt] = __builtin_amdgcn_mfma_f32_16x16x32_bf16(al, b, acc[nt], 0, 0, 0);
        }
    }
    #pragma unroll
    for (int nt = 0; nt < NT; ++nt) {
        const int oc = (nt0 + nt) * 16 + l15;
        if (oc < 98) {
            #pragma unroll
            for (int r = 0; r < 4; ++r)
                Zo[((size_t)d * 256 + m0 + r) * 98 + oc] = acc[nt][r];
        }
    }
}

// ============ stage-1 GEMMs, K-split x4 + N-split x2: grid 3136 =====
// Zp partial: [ks][49][256][98]; Y1 partial: [ks][49][256][64]
__global__ __launch_bounds__(256) void k_gemms1(
    const short* __restrict__ Xf, const short* __restrict__ OWbf,
    const short* __restrict__ W1f,
    float* __restrict__ Zp, float* __restrict__ Y1)
{
    const int tid = threadIdx.x;
    const int wv = tid >> 6;
    const int l  = tid & 63;
    const int l15 = l & 15, l4 = l >> 4;

    // XCD-aware: 4 M-sibling blocks (same B-slice) consecutive -> same XCD
    const int bid = blockIdx.x;                  // 0..3135
    const int work = (bid & 7) * 392 + (bid >> 3);
    const int x    = work & 3;
    const int rest = work >> 2;                  // 0..783
    const int ks   = rest / 196;
    const int by   = rest - ks * 196;

    const int mtile = x * 4 + wv;
    const int kb0 = ks * 8;
    const int lofs = l4 * 16 + l15;

    const bf16x8* Ah = (const bf16x8*)Xf + (size_t)mtile * 2048 + lofs;
    const bf16x8* Al = Ah + 32768;
    const int m0 = mtile * 16 + l4 * 4;

    if (by < 98) {
        const int d   = by >> 1;
        const int nth = by & 1;
        float* Zo = Zp + (size_t)ks * 1229312;
        if (nth == 0) {
            const bf16x8* Bb = (const bf16x8*)OWbf + (size_t)(d * 7) * 2048 + lofs;
            d_zpart<4>(Ah, Al, Bb, Zo, d, m0, l15, 0, kb0);
        } else {
            const bf16x8* Bb = (const bf16x8*)OWbf + (size_t)(d * 7 + 4) * 2048 + lofs;
            d_zpart<3>(Ah, Al, Bb, Zo, d, m0, l15, 4, kb0);
        }
    } else {
        const int dd  = by - 98;
        const int d   = dd >> 1;
        const int nt0 = (dd & 1) * 2;
        const bf16x8* Bh = (const bf16x8*)W1f + (size_t)(d * 4 + nt0) * 2048 + lofs;
        const bf16x8* Bl = Bh + 401408;
        f32x4 acc[2];
        #pragma unroll
        for (int nt = 0; nt < 2; ++nt) acc[nt] = (f32x4){0.f, 0.f, 0.f, 0.f};
        #pragma unroll
        for (int i = 0; i < 8; ++i) {
            const int kb = kb0 + i;
            const bf16x8 ah = Ah[kb * 64];
            const bf16x8 al = Al[kb * 64];
            #pragma unroll
            for (int nt = 0; nt < 2; ++nt) {
                const bf16x8 bh = Bh[nt * 2048 + kb * 64];
                const bf16x8 bl = Bl[nt * 2048 + kb * 64];
                acc[nt] = __builtin_amdgcn_mfma_f32_16x16x32_bf16(ah, bh, acc[nt], 0, 0, 0);
                acc[nt] = __builtin_amdgcn_mfma_f32_16x16x32_bf16(ah, bl, acc[nt], 0, 0, 0);
                acc[nt] = __builtin_amdgcn_mfma_f32_16x16x32_bf16(al, bh, acc[nt], 0, 0, 0);
            }
        }
        float* Yo = Y1 + (size_t)ks * 802816;
        #pragma unroll
        for (int nt = 0; nt < 2; ++nt) {
            const int f = (nt0 + nt) * 16 + l15;
            #pragma unroll
            for (int r = 0; r < 4; ++r)
                Yo[((size_t)d * 256 + m0 + r) * 64 + f] = acc[nt][r];
        }
    }
}

// ============ sparams device fn ============
__device__ __forceinline__ void d_bilin(
    const float accy, const float accx, const int hp, const int wp,
    const int b, const int k, const int H, const int W, const int Hp, const int Wp,
    float& s_out, int& src_out)
{
    const float y = (float)(hp + (k / 7) - 3) + accy;
    const float x = (float)(wp + (k % 7) - 3) + accx;
    const float fy0 = floorf(y), fx0 = floorf(x);
    const int iy0 = (int)fy0, ix0 = (int)fx0;
    const float wy1 = y - fy0, wx1 = x - fx0;
    int ye, xe; float wy, wx;
    if (iy0 & 1) { ye = iy0 + 1; wy = wy1; } else { ye = iy0; wy = 1.f - wy1; }
    if (ix0 & 1) { xe = ix0 + 1; wx = wx1; } else { xe = ix0; wx = 1.f - wx1; }
    float s = wy * wx;
    int src = 0;
    if (ye >= 0 && ye < Hp && xe >= 0 && xe < Wp)
        src = (b * H + (ye >> 1)) * W + (xe >> 1);
    else
        s = 0.f;
    s_out = s;
    src_out = src;
}

// ============ stage-1 combine (fused sparams_z1, 4 partials) ============
__global__ __launch_bounds__(256) void k_combine1(
    const float* __restrict__ Y, const float* __restrict__ Zp,
    const float* __restrict__ OB, const float* __restrict__ bias,
    short* __restrict__ xhi, short* __restrict__ xlo)
{
    __shared__ float ss[4][49];
    __shared__ int   isrc[4][49];
    const int tid = threadIdx.x;

    if (tid < 196) {
        const int p = tid / 49, k = tid - p * 49;
        const int pixg = blockIdx.x * 4 + p;
        const int b   = pixg >> 9;
        const int rem = pixg & 511;
        const int hp  = rem >> 5;
        const int wp  = rem & 31;
        float accy = OB[2 * k], accx = OB[2 * k + 1];
        const int di0 = (hp + 1) & 1, dj0 = (wp + 1) & 1;
        for (int di = di0; di < 7; di += 2) {
            const int yp = hp + di - 3;
            if ((unsigned)yp >= 16u) continue;
            const int ys = yp >> 1;
            for (int dj = dj0; dj < 7; dj += 2) {
                const int xp = wp + dj - 3;
                if ((unsigned)xp >= 32u) continue;
                const int xs = xp >> 1;
                const size_t o = ((size_t)((di * 7 + dj) * 256 + (b * 8 + ys) * 16 + xs)) * 98 + 2 * k;
                accy += (Zp[o] + Zp[o + 1229312]) + (Zp[o + 2458624] + Zp[o + 3687936]);
                accx += (Zp[o + 1] + Zp[o + 1229313]) + (Zp[o + 2458625] + Zp[o + 3687937]);
            }
        }
        d_bilin(accy, accx, hp, wp, b, k, 8, 16, 16, 32, ss[p][k], isrc[p][k]);
    }
    __syncthreads();

    const int f = tid & 63;
    const int p = tid >> 6;
    const int pixg = blockIdx.x * 4 + p;
    float acc = bias[f];
    #pragma unroll 7
    for (int k = 0; k < K49; ++k) {
        const size_t yo = ((size_t)k * 256 + isrc[p][k]) * 64 + f;
        const float yv = (Y[yo] + Y[yo + 802816]) + (Y[yo + 1605632] + Y[yo + 2408448]);
        acc = fmaf(ss[p][k], yv, acc);
    }
    const float v = fmaxf(acc, 0.f);
    const size_t o = (size_t)pixg * 64 + f;
    const short h = f2bf(v);
    xhi[o] = h;
    xlo[o] = f2bf(v - bf2f(h));
}

// ============ stages 2-3 GEMMs merged (offmfma + ygemm23): grid (gx, 53) ====
template<int C, int F>
__global__ __launch_bounds__(256) void k_gemms23(
    const short* __restrict__ Xbf, const short* __restrict__ OWf,
    const short* __restrict__ Wf,
    float* __restrict__ off, float* __restrict__ Y,
    const int H, const int W, const int Hp, const int Wp,
    const int M, const int nX)
{
    const int tid = threadIdx.x;
    const int wv = tid >> 6;
    const int l  = tid & 63;
    const int l15 = l & 15, l4 = l >> 4;
    const int by = blockIdx.y;

    if (by < 4) {
        const int cls = by;
        const int pi = cls >> 1, rho = cls & 1;
        const int NRc = pi ? 4 : 3, NCc = rho ? 4 : 3;
        const int T = NRc * NCc;
        int nkb, clsoff;
        if (C == 64) { nkb = T * 2; clsoff = cls == 0 ? 0 : cls == 1 ? 18 : cls == 2 ? 42 : 66; }
        else         { nkb = T;     clsoff = cls == 0 ? 0 : cls == 1 ? 9  : cls == 2 ? 21 : 33; }

        const int Wt16 = W >> 4;
        const int mt = blockIdx.x * 4 + wv;
        const int rloc = mt / Wt16, xt = mt - rloc * Wt16;
        const int b = rloc / H;
        const int ysp = rloc - b * H;

        f32x4 acc[7];
        #pragma unroll
        for (int nt = 0; nt < 7; ++nt) acc[nt] = (f32x4){0.f, 0.f, 0.f, 0.f};

        const bf16x8* Bbase = (const bf16x8*)OWf + ((size_t)clsoff * 7) * 64 + l4 * 16 + l15;

        for (int kb = 0; kb < nkb; ++kb) {
            int tl, c0;
            if (C == 64) { tl = kb >> 1; c0 = ((kb & 1) << 5) + l4 * 8; }
            else         { tl = kb;      c0 = l4 * 8; }
            int iy, ix;
            if (NCc == 4) { iy = tl >> 2; ix = tl & 3; }
            else          { iy = tl / 3;  ix = tl - iy * 3; }
            const int ys = ysp + iy - 1;
            const int xs = xt * 16 + l15 + ix - 1;
            bf16x8 ah = {0, 0, 0, 0, 0, 0, 0, 0};
            bf16x8 al = {0, 0, 0, 0, 0, 0, 0, 0};
            if ((unsigned)ys < (unsigned)H && (unsigned)xs < (unsigned)W) {
                const size_t a = ((size_t)(b * H + ys) * W + xs) * C + c0;
                ah = *(const bf16x8*)(Xbf + a);
                al = *(const bf16x8*)(Xbf + nX + a);
            }
            const bf16x8* Bb = Bbase + (size_t)kb * 7 * 64;
            #pragma unroll
            for (int nt = 0; nt < 7; ++nt) {
                const bf16x8 bf = Bb[nt * 64];
                acc[nt] = __builtin_amdgcn_mfma_f32_16x16x32_bf16(ah, bf, acc[nt], 0, 0, 0);
                acc[nt] = __builtin_amdgcn_mfma_f32_16x16x32_bf16(al, bf, acc[nt], 0, 0, 0);
            }
        }

        const int hp = 2 * ysp + pi;
        const int wpbase = (xt << 5) + rho;
        const int pixrow = (b * Hp + hp) * Wp + wpbase;
        #pragma unroll
        for (int nt = 0; nt < 7; ++nt) {
            const int oc = nt * 16 + l15;
            if (oc < 98) {
                #pragma unroll
                for (int r = 0; r < 4; ++r) {
                    const int m = l4 * 4 + r;
                    off[(size_t)(pixrow + 2 * m) * 98 + oc] = acc[nt][r];
                }
            }
        }
    } else {
        constexpr int KB = C / 32;
        constexpr int NT = F / 16;
        constexpr int PLANEFRAG = 49 * NT * KB * 64;
        const int d = by - 4;
        const int mtile = blockIdx.x * 4 + wv;
        const short* Arow = Xbf + (size_t)(mtile * 16 + l15) * C + l4 * 8;

        f32x4 acc[NT];
        #pragma unroll
        for (int nt = 0; nt < NT; ++nt) acc[nt] = (f32x4){0.f, 0.f, 0.f, 0.f};

        #pragma unroll
        for (int kb = 0; kb < KB; ++kb) {
            const bf16x8 ah = *(const bf16x8*)(Arow + kb * 32);
            const bf16x8 al = *(const bf16x8*)(Arow + nX + kb * 32);
            #pragma unroll
            for (int nt = 0; nt < NT; ++nt) {
                const size_t fi = ((size_t)(d * NT + nt) * KB + kb) * 64 + l4 * 16 + l15;
                const bf16x8 bh = ((const bf16x8*)Wf)[fi];
                const bf16x8 bl = ((const bf16x8*)Wf)[fi + PLANEFRAG];
                acc[nt] = __builtin_amdgcn_mfma_f32_16x16x32_bf16(ah, bh, acc[nt], 0, 0, 0);
                acc[nt] = __builtin_amdgcn_mfma_f32_16x16x32_bf16(ah, bl, acc[nt], 0, 0, 0);
                acc[nt] = __builtin_amdgcn_mfma_f32_16x16x32_bf16(al, bh, acc[nt], 0, 0, 0);
            }
        }

        const int m0 = mtile * 16 + l4 * 4;
        #pragma unroll
        for (int nt = 0; nt < NT; ++nt) {
            const int f = nt * 16 + l15;
            #pragma unroll
            for (int r = 0; r < 4; ++r)
                Y[((size_t)d * M + m0 + r) * F + f] = acc[nt][r];
        }
    }
}

// ============ stages 2-3 combine (fused sparams, optional Y4) ============
template<int F, bool DO_Y4>
__global__ __launch_bounds__(256) void k_combine23(
    const float* __restrict__ Y, const float* __restrict__ off,
    const float* __restrict__ OB, const float* __restrict__ bias,
    short* __restrict__ xhi, short* __restrict__ xlo,
    const float* __restrict__ w4, float* __restrict__ Y4,
    const int npix, const int nsrc,
    const int H, const int W, const int Hp, const int Wp)
{
    constexpr int PPB = 256 / F;
    __shared__ float ss[PPB][49];
    __shared__ int   isrc[PPB][49];
    __shared__ float xv[DO_Y4 ? PPB : 1][DO_Y4 ? 17 : 1];
    __shared__ float w4s[DO_Y4 ? 784 : 1];
    const int tid = threadIdx.x;
    const int HWp = Hp * Wp;

    if (DO_Y4) {
        for (int t = tid; t < 784; t += 256) w4s[t] = w4[t];
    }
    for (int t = tid; t < PPB * 49; t += 256) {
        const int p = t / 49, k = t - p * 49;
        const int pixg = blockIdx.x * PPB + p;
        const float accy = OB[2 * k]     + off[(size_t)pixg * 98 + 2 * k];
        const float accx = OB[2 * k + 1] + off[(size_t)pixg * 98 + 2 * k + 1];
        const int b = pixg / HWp;
        const int rem = pixg - b * HWp;
        const int hp = rem / Wp;
        const int wp = rem - hp * Wp;
        d_bilin(accy, accx, hp, wp, b, k, H, W, Hp, Wp, ss[p][k], isrc[p][k]);
    }
    __syncthreads();

    const int f = tid % F;
    const int p2 = tid / F;
    const int pixg2 = blockIdx.x * PPB + p2;
    float acc = bias[f];
    #pragma unroll 7
    for (int k = 0; k < K49; ++k)
        acc = fmaf(ss[p2][k], Y[((size_t)k * nsrc + isrc[p2][k]) * F + f], acc);
    const float v = fmaxf(acc, 0.f);
    const size_t o = (size_t)pixg2 * F + f;
    const short h = f2bf(v);
    xhi[o] = h;
    xlo[o] = f2bf(v - bf2f(h));

    if (DO_Y4) {
        xv[p2][f] = v;
        __syncthreads();
        for (int t = tid; t < PPB * 49; t += 256) {
            const int p = t / 49, k = t - p * 49;
            float d = 0.f;
            #pragma unroll
            for (int f2 = 0; f2 < 16; ++f2)
                d = fmaf(xv[p][f2], w4s[k * 16 + f2], d);
            Y4[(size_t)k * npix + blockIdx.x * PPB + p] = d;
        }
    }
}

// ============ stage 4 FUSED: implicit-GEMM offsets (LDS) + sparams + dconv ==
// grid (256, 4); block handles 64 pixels of one parity class.
__global__ __launch_bounds__(256) void k_stage4(
    const short* __restrict__ Xbf, const short* __restrict__ OWf,
    const float* __restrict__ Y4,       // [49][nsrc]
    const float* __restrict__ OB, const float* __restrict__ bias,
    float* __restrict__ out, const int nX)
{
    constexpr int C = 16, H = 64, W = 128, Hp = 128, Wp = 256;
    __shared__ float offs[64][98];
    __shared__ float OBs[98];

    const int tid = threadIdx.x;
    const int wv = tid >> 6;
    const int l  = tid & 63;
    const int l15 = l & 15, l4 = l >> 4;
    const int cls = blockIdx.y;
    const int pi = cls >> 1, rho = cls & 1;
    const int NRc = pi ? 4 : 3, NCc = rho ? 4 : 3;
    const int T = NRc * NCc;
    const int nkb = (T + 1) >> 1;
    const int clsoff = cls == 0 ? 0 : cls == 1 ? 5 : cls == 2 ? 11 : 17;

    if (tid < 98) OBs[tid] = OB[tid];

    // ---- phase 1: implicit-GEMM MFMA, acc -> LDS ----
    const int mt = blockIdx.x * 4 + wv;
    const int rloc = mt >> 3, xt = mt & 7;     // Wt16 = 8
    const int b = rloc / H;
    const int ysp = rloc - b * H;

    f32x4 acc[7];
    #pragma unroll
    for (int nt = 0; nt < 7; ++nt) acc[nt] = (f32x4){0.f, 0.f, 0.f, 0.f};

    const bf16x8* Bbase = (const bf16x8*)OWf + ((size_t)clsoff * 7) * 64 + l4 * 16 + l15;

    for (int kb = 0; kb < nkb; ++kb) {
        int tl = kb * 2 + (l4 >> 1);
        const int c0 = (l4 & 1) * 8;
        if (tl >= T) tl = T - 1;               // B is zero there; A clamp for bounds only
        int iy, ix;
        if (NCc == 4) { iy = tl >> 2; ix = tl & 3; }
        else          { iy = tl / 3;  ix = tl - iy * 3; }
        const int ys = ysp + iy - 1;
        const int xs = xt * 16 + l15 + ix - 1;
        bf16x8 ah = {0, 0, 0, 0, 0, 0, 0, 0};
        bf16x8 al = {0, 0, 0, 0, 0, 0, 0, 0};
        if ((unsigned)ys < (unsigned)H && (unsigned)xs < (unsigned)W) {
            const size_t a = ((size_t)(b * H + ys) * W + xs) * C + c0;
            ah = *(const bf16x8*)(Xbf + a);
            al = *(const bf16x8*)(Xbf + nX + a);
        }
        const bf16x8* Bb = Bbase + (size_t)kb * 7 * 64;
        #pragma unroll
        for (int nt = 0; nt < 7; ++nt) {
            const bf16x8 bf = Bb[nt * 64];
            acc[nt] = __builtin_amdgcn_mfma_f32_16x16x32_bf16(ah, bf, acc[nt], 0, 0, 0);
            acc[nt] = __builtin_amdgcn_mfma_f32_16x16x32_bf16(al, bf, acc[nt], 0, 0, 0);
        }
    }

    #pragma unroll
    for (int nt = 0; nt < 7; ++nt) {
        const int oc = nt * 16 + l15;
        if (oc < 98) {
            #pragma unroll
            for (int r = 0; r < 4; ++r)
                offs[wv * 16 + l4 * 4 + r][oc] = acc[nt][r];
        }
    }
    __syncthreads();

    // ---- phase 2: sparams + gather-combine (4 lanes per pixel) ----
    const int p  = tid >> 2;                   // 0..63 block-local pixel
    const int tq = tid & 3;
    const int t0 = (tq == 0) ? 0 : 13 + (tq - 1) * 12;
    const int t1 = t0 + ((tq == 0) ? 13 : 12);

    const int wv_p = p >> 4;
    const int m_p  = p & 15;
    const int mt_p = blockIdx.x * 4 + wv_p;
    const int rloc_p = mt_p >> 3, xt_p = mt_p & 7;
    const int b_p = rloc_p / H;
    const int ysp_p = rloc_p - b_p * H;
    const int hp = 2 * ysp_p + pi;
    const int wp = (xt_p << 5) + rho + 2 * m_p;
    const int pixg = (b_p * Hp + hp) * Wp + wp;

    float acc2 = 0.f;
    for (int k = t0; k < t1; ++k) {
        const float offy = offs[p][2 * k]     + OBs[2 * k];
        const float offx = offs[p][2 * k + 1] + OBs[2 * k + 1];
        float s; int src;
        d_bilin(offy, offx, hp, wp, b_p, k, H, W, Hp, Wp, s, src);
        acc2 = fmaf(s, Y4[(size_t)k * 16384 + src], acc2);
    }
    acc2 += __shfl_xor(acc2, 1);
    acc2 += __shfl_xor(acc2, 2);
    if (tq == 0) out[pixg] = acc2 + bias[0];
}

extern "C" void kernel_launch(void* const* d_in, const int* in_sizes, int n_in,
                              void* d_out, int out_size, void* d_ws, size_t ws_size,
                              hipStream_t stream) {
    const float* z   = (const float*)d_in[0];
    const float* dw  = (const float*)d_in[1];
    const float* db  = (const float*)d_in[2];
    const float* ow1 = (const float*)d_in[3];
    const float* ob1 = (const float*)d_in[4];
    const float* w1  = (const float*)d_in[5];
    const float* b1  = (const float*)d_in[6];
    const float* ow2 = (const float*)d_in[7];
    const float* ob2 = (const float*)d_in[8];
    const float* w2  = (const float*)d_in[9];
    const float* b2  = (const float*)d_in[10];
    const float* ow3 = (const float*)d_in[11];
    const float* ob3 = (const float*)d_in[12];
    const float* w3  = (const float*)d_in[13];
    const float* b3  = (const float*)d_in[14];
    const float* ow4 = (const float*)d_in[15];
    const float* ob4 = (const float*)d_in[16];
    const float* w4  = (const float*)d_in[17];
    const float* b4  = (const float*)d_in[18];

    // workspace layout: ~92 MB, no aliasing (ws_size = 256 MiB)
    float* ws   = (float*)d_ws;
    short* Xf   = (short*)ws;                    // 524,288 sh
    float* Zp   = ws + 262144;                   // 4 x 1,229,312 = 4,917,248
    float* Y1   = Zp + 4917248;                  // 4 x 802,816 = 3,211,264
    float* Y2   = Y1 + 3211264;                  // 1,605,632
    float* Y3   = Y2 + 1605632;                  // 3,211,264
    float* Y4   = Y3 + 3211264;                  // 802,816
    short* Xbf1 = (short*)(Y4 + 802816);         // 131,072 sh
    short* Xbf2 = Xbf1 + 131072;                 // 262,144 sh
    short* Xbf3 = Xbf2 + 262144;                 // 524,288 sh
    float* off2 = (float*)(Xbf3 + 524288);       // 401,408
    float* off3 = off2 + 401408;                 // 1,605,632
    short* OWbf = (short*)(off3 + 1605632);      // 5,619,712 sh
    short* W1f  = OWbf + 5619712;                // 6,422,528 sh
    short* OWf2 = W1f + 6422528;                 // 351,232 sh
    short* W2f  = OWf2 + 351232;                 // 200,704 sh
    short* OWf3 = W2f + 200704;                  // 175,616 sh
    short* W3f  = OWf3 + 175616;                 // 50,176 sh
    short* OWf4 = W3f + 50176;                   // 89,600 sh

    float* out = (float*)d_out;

    // 1) dense+cvt AND all weight packing (independent, one launch)
    k_prep<<<7294, 256, 0, stream>>>(z, dw, db, Xf, ow1, w1, ow2, w2, ow3, w3, ow4,
                                     OWbf, W1f, OWf2, W2f, OWf3, W3f, OWf4);

    // 2) stage-1 GEMMs (offset + Y; K-split x4, N-split x2, compile-time NT)
    k_gemms1<<<3136, 256, 0, stream>>>(Xf, OWbf, W1f, Zp, Y1);

    // 3) stage-1 combine (fused sparams_z1, sums 4 partials) -> Xbf1
    k_combine1<<<256, 256, 0, stream>>>(Y1, Zp, ob1, b1, Xbf1, Xbf1 + 65536);

    // 4) stage-2 GEMMs (offmfma + ygemm, merged)
    k_gemms23<64, 32><<<dim3(16, 53), 256, 0, stream>>>(
        Xbf1, OWf2, W2f, off2, Y2, 16, 32, 32, 64, 1024, 65536);

    // 5) stage-2 combine -> Xbf2
    k_combine23<32, false><<<512, 256, 0, stream>>>(
        Y2, off2, ob2, b2, Xbf2, Xbf2 + 131072, nullptr, nullptr, 4096, 1024, 16, 32, 32, 64);

    // 6) stage-3 GEMMs
    k_gemms23<32, 16><<<dim3(64, 53), 256, 0, stream>>>(
        Xbf2, OWf3, W3f, off3, Y3, 32, 64, 64, 128, 4096, 131072);

    // 7) stage-3 combine + Y4 -> Xbf3, Y4
    k_combine23<16, true><<<1024, 256, 0, stream>>>(
        Y3, off3, ob3, b3, Xbf3, Xbf3 + 262144, w4, Y4, 16384, 4096, 32, 64, 64, 128);

    // 8) stage-4 fused: offsets (MFMA->LDS) + sparams + dconv -> out
    k_stage4<<<dim3(256, 4), 256, 0, stream>>>(Xbf3, OWf4, Y4, ob4, b4, out, 262144);
}

// Round 17
// 137.666 us; speedup vs baseline: 1.0909x; 1.0006x over previous
//
#include <hip/hip_runtime.h>
#include <hip/hip_bf16.h>

#define K49 49

typedef short bf16x8 __attribute__((ext_vector_type(8)));
typedef float f32x4 __attribute__((ext_vector_type(4)));

__device__ __forceinline__ short f2bf(float x) {
    __hip_bfloat16 h = __float2bfloat16(x);
    return __builtin_bit_cast(short, h);
}
__device__ __forceinline__ float bf2f(short s) {
    unsigned u = ((unsigned)(unsigned short)s) << 16;
    return __builtin_bit_cast(float, u);
}

// ==================== weight packing (device fns) ====================
__device__ __forceinline__ void d_pack_ow1(
    const int gid, const float* __restrict__ OW, short* __restrict__ OWbf)
{
    const int ni = gid & 15;
    int t = gid >> 4;
    const int kg = t & 3;  t >>= 2;
    const int kb = t & 31; t >>= 5;
    const int nt = t % 7;
    const int d  = t / 7;
    const int oc = nt * 16 + ni;
    short h[8];
    if (oc < 98) {
        const int c0 = kb * 32 + kg * 8;
        #pragma unroll
        for (int j = 0; j < 8; ++j)
            h[j] = f2bf(OW[((size_t)d * 1024 + c0 + j) * 98 + oc]);
    } else {
        #pragma unroll
        for (int j = 0; j < 8; ++j) h[j] = 0;
    }
    *(bf16x8*)(OWbf + (size_t)gid * 8) = *(bf16x8*)h;
}

template<int C, int F>
__device__ __forceinline__ void d_pack_w(
    const int gid, const float* __restrict__ Wt, short* __restrict__ Wf)
{
    constexpr int KB = C / 32;
    constexpr int NT = F / 16;
    constexpr int PLANE = 49 * NT * KB * 4 * 16 * 8;   // shorts
    const int ni = gid & 15;
    int t = gid >> 4;
    const int kg = t & 3; t >>= 2;
    const int kb = t % KB; t /= KB;
    const int nt = t % NT;
    const int d  = t / NT;
    const int f = nt * 16 + ni;
    const int c0 = kb * 32 + kg * 8;
    short hi[8], lo[8];
    #pragma unroll
    for (int j = 0; j < 8; ++j) {
        const float v = Wt[((size_t)d * C + c0 + j) * F + f];
        hi[j] = f2bf(v);
        lo[j] = f2bf(v - bf2f(hi[j]));
    }
    *(bf16x8*)(Wf + (size_t)gid * 8) = *(bf16x8*)hi;
    *(bf16x8*)(Wf + PLANE + (size_t)gid * 8) = *(bf16x8*)lo;
}

template<int C>
__device__ __forceinline__ void d_pack_owf(
    const int gid, const float* __restrict__ OW, short* __restrict__ OWf)
{
    const int j = gid & 7;
    int t = gid >> 3;
    const int fi = t & 63; t >>= 6;
    const int nt = t % 7;
    const int kbg = t / 7;
    const int ni = fi & 15, kg = fi >> 4;

    int cum1, cum2, cum3;
    if (C == 64)      { cum1 = 18; cum2 = 42; cum3 = 66; }
    else if (C == 32) { cum1 = 9;  cum2 = 21; cum3 = 33; }
    else              { cum1 = 5;  cum2 = 11; cum3 = 17; }
    int cls, kb0;
    if (kbg < cum1)      { cls = 0; kb0 = 0; }
    else if (kbg < cum2) { cls = 1; kb0 = cum1; }
    else if (kbg < cum3) { cls = 2; kb0 = cum2; }
    else                 { cls = 3; kb0 = cum3; }
    const int kbl = kbg - kb0;
    const int pi = cls >> 1, rho = cls & 1;
    const int NRc = pi ? 4 : 3, NCc = rho ? 4 : 3;
    const int T = NRc * NCc;

    const int k = kbl * 32 + kg * 8 + j;
    const int tl = k / C, c = k - tl * C;
    const int oc = nt * 16 + ni;
    float v = 0.f;
    if (tl < T && oc < 98) {
        const int iy = tl / NCc, ix = tl - iy * NCc;
        const int d = (1 - pi + 2 * iy) * 7 + (1 - rho + 2 * ix);
        v = OW[((size_t)d * C + c) * 98 + oc];
    }
    OWf[gid] = f2bf(v);
}

// ==================== mega prep kernel: dense+cvt AND all weight packs =====
// Xf layout (bf16): [plane(2)][mtile(16)][kb(32)][kg(4)][mi(16)][8]
__global__ __launch_bounds__(256) void k_prep(
    const float* __restrict__ z, const float* __restrict__ Wd,
    const float* __restrict__ bd, short* __restrict__ Xf,
    const float* __restrict__ ow1, const float* __restrict__ w1,
    const float* __restrict__ ow2, const float* __restrict__ w2,
    const float* __restrict__ ow3, const float* __restrict__ w3,
    const float* __restrict__ ow4,
    short* OWbf, short* W1f, short* OWf2, short* W2f,
    short* OWf3, short* W3f, short* OWf4)
{
    const int bid0 = blockIdx.x;
    const int tid = threadIdx.x;
    __shared__ float zs[256];
    if (bid0 < 512) {
        const int D = 131072;
        zs[tid] = z[tid];
        __syncthreads();
        const int n = bid0 * 256 + tid;
        const float bb = bd[n];
        float a0 = bb, a1 = bb;
        #pragma unroll 8
        for (int kk = 0; kk < 128; ++kk) {
            const float w = Wd[kk * D + n];
            a0 = fmaf(zs[kk], w, a0);
            a1 = fmaf(zs[128 + kk], w, a1);
        }
        a0 = fmaxf(a0, 0.f);
        a1 = fmaxf(a1, 0.f);
        const int c = n & 1023;
        const int m0 = n >> 10;
        const int kb = c >> 5, kg = (c >> 3) & 3, j = c & 7;
        const size_t base = ((size_t)kb * 4 + kg) * 16 * 8 + j;
        {
            const size_t dst = ((size_t)(m0 >> 4) * 2048) * 8 + base + (size_t)(m0 & 15) * 8;
            const short h = f2bf(a0);
            Xf[dst] = h;
            Xf[262144 + dst] = f2bf(a0 - bf2f(h));
        }
        {
            const int m1 = m0 + 128;
            const size_t dst = ((size_t)(m1 >> 4) * 2048) * 8 + base + (size_t)(m1 & 15) * 8;
            const short h = f2bf(a1);
            Xf[dst] = h;
            Xf[262144 + dst] = f2bf(a1 - bf2f(h));
        }
        return;
    }
    const int bid = bid0 - 512;
    if (bid < 2744)      d_pack_ow1((bid) * 256 + tid, ow1, OWbf);
    else if (bid < 4312) d_pack_w<1024, 64>((bid - 2744) * 256 + tid, w1, W1f);
    else if (bid < 5684) d_pack_owf<64>((bid - 4312) * 256 + tid, ow2, OWf2);
    else if (bid < 5733) d_pack_w<64, 32>((bid - 5684) * 256 + tid, w2, W2f);
    else if (bid < 6419) d_pack_owf<32>((bid - 5733) * 256 + tid, ow3, OWf3);
    else if (bid < 6432) { const int g = (bid - 6419) * 256 + tid; if (g < 3136) d_pack_w<32, 16>(g, w3, W3f); }
    else                 d_pack_owf<16>((bid - 6432) * 256 + tid, ow4, OWf4);
}

// ============ Z-branch body, compile-time NT so everything unrolls =========
template<int NT>
__device__ __forceinline__ void d_zpart(
    const bf16x8* __restrict__ Ah, const bf16x8* __restrict__ Al,
    const bf16x8* __restrict__ Bb, float* __restrict__ Zo,
    const int d, const int m0, const int l15, const int nt0, const int kb0)
{
    f32x4 acc[NT];
    #pragma unroll
    for (int nt = 0; nt < NT; ++nt) acc[nt] = (f32x4){0.f, 0.f, 0.f, 0.f};
    #pragma unroll
    for (int i = 0; i < 8; ++i) {
        const int kb = kb0 + i;
        const bf16x8 ah = Ah[kb * 64];
        const bf16x8 al = Al[kb * 64];
        #pragma unroll
        for (int nt = 0; nt < NT; ++nt) {
            const bf16x8 b = Bb[(size_t)nt * 2048 + kb * 64];
            acc[nt] = __builtin_amdgcn_mfma_f32_16x16x32_bf16(ah, b, acc[nt], 0, 0, 0);
            acc[nt] = __builtin_amdgcn_mfma_f32_16x16x32_bf16(al, b, acc[nt], 0, 0, 0);
        }
    }
    #pragma unroll
    for (int nt = 0; nt < NT; ++nt) {
        const int oc = (nt0 + nt) * 16 + l15;
        if (oc < 98) {
            #pragma unroll
            for (int r = 0; r < 4; ++r)
                Zo[((size_t)d * 256 + m0 + r) * 98 + oc] = acc[nt][r];
        }
    }
}

// ============ stage-1 GEMMs, K-split x4 + N-split x2: grid 3136 =====
// Zp partial: [ks][49][256][98]; Y1 partial: [ks][49][256][64]
__global__ __launch_bounds__(256) void k_gemms1(
    const short* __restrict__ Xf, const short* __restrict__ OWbf,
    const short* __restrict__ W1f,
    float* __restrict__ Zp, float* __restrict__ Y1)
{
    const int tid = threadIdx.x;
    const int wv = tid >> 6;
    const int l  = tid & 63;
    const int l15 = l & 15, l4 = l >> 4;

    // XCD-aware: 4 M-sibling blocks (same B-slice) consecutive -> same XCD
    const int bid = blockIdx.x;                  // 0..3135
    const int work = (bid & 7) * 392 + (bid >> 3);
    const int x    = work & 3;
    const int rest = work >> 2;                  // 0..783
    const int ks   = rest / 196;
    const int by   = rest - ks * 196;

    const int mtile = x * 4 + wv;
    const int kb0 = ks * 8;
    const int lofs = l4 * 16 + l15;

    const bf16x8* Ah = (const bf16x8*)Xf + (size_t)mtile * 2048 + lofs;
    const bf16x8* Al = Ah + 32768;
    const int m0 = mtile * 16 + l4 * 4;

    if (by < 98) {
        const int d   = by >> 1;
        const int nth = by & 1;
        float* Zo = Zp + (size_t)ks * 1229312;
        if (nth == 0) {
            const bf16x8* Bb = (const bf16x8*)OWbf + (size_t)(d * 7) * 2048 + lofs;
            d_zpart<4>(Ah, Al, Bb, Zo, d, m0, l15, 0, kb0);
        } else {
            const bf16x8* Bb = (const bf16x8*)OWbf + (size_t)(d * 7 + 4) * 2048 + lofs;
            d_zpart<3>(Ah, Al, Bb, Zo, d, m0, l15, 4, kb0);
        }
    } else {
        const int dd  = by - 98;
        const int d   = dd >> 1;
        const int nt0 = (dd & 1) * 2;
        const bf16x8* Bh = (const bf16x8*)W1f + (size_t)(d * 4 + nt0) * 2048 + lofs;
        const bf16x8* Bl = Bh + 401408;
        f32x4 acc[2];
        #pragma unroll
        for (int nt = 0; nt < 2; ++nt) acc[nt] = (f32x4){0.f, 0.f, 0.f, 0.f};
        #pragma unroll
        for (int i = 0; i < 8; ++i) {
            const int kb = kb0 + i;
            const bf16x8 ah = Ah[kb * 64];
            const bf16x8 al = Al[kb * 64];
            #pragma unroll
            for (int nt = 0; nt < 2; ++nt) {
                const bf16x8 bh = Bh[nt * 2048 + kb * 64];
                const bf16x8 bl = Bl[nt * 2048 + kb * 64];
                acc[nt] = __builtin_amdgcn_mfma_f32_16x16x32_bf16(ah, bh, acc[nt], 0, 0, 0);
                acc[nt] = __builtin_amdgcn_mfma_f32_16x16x32_bf16(ah, bl, acc[nt], 0, 0, 0);
                acc[nt] = __builtin_amdgcn_mfma_f32_16x16x32_bf16(al, bh, acc[nt], 0, 0, 0);
            }
        }
        float* Yo = Y1 + (size_t)ks * 802816;
        #pragma unroll
        for (int nt = 0; nt < 2; ++nt) {
            const int f = (nt0 + nt) * 16 + l15;
            #pragma unroll
            for (int r = 0; r < 4; ++r)
                Yo[((size_t)d * 256 + m0 + r) * 64 + f] = acc[nt][r];
        }
    }
}

// ============ sparams device fn ============
__device__ __forceinline__ void d_bilin(
    const float accy, const float accx, const int hp, const int wp,
    const int b, const int k, const int H, const int W, const int Hp, const int Wp,
    float& s_out, int& src_out)
{
    const float y = (float)(hp + (k / 7) - 3) + accy;
    const float x = (float)(wp + (k % 7) - 3) + accx;
    const float fy0 = floorf(y), fx0 = floorf(x);
    const int iy0 = (int)fy0, ix0 = (int)fx0;
    const float wy1 = y - fy0, wx1 = x - fx0;
    int ye, xe; float wy, wx;
    if (iy0 & 1) { ye = iy0 + 1; wy = wy1; } else { ye = iy0; wy = 1.f - wy1; }
    if (ix0 & 1) { xe = ix0 + 1; wx = wx1; } else { xe = ix0; wx = 1.f - wx1; }
    float s = wy * wx;
    int src = 0;
    if (ye >= 0 && ye < Hp && xe >= 0 && xe < Wp)
        src = (b * H + (ye >> 1)) * W + (xe >> 1);
    else
        s = 0.f;
    s_out = s;
    src_out = src;
}

// ============ stage-1 combine (fused sparams_z1, 4 partials) ============
__global__ __launch_bounds__(256) void k_combine1(
    const float* __restrict__ Y, const float* __restrict__ Zp,
    const float* __restrict__ OB, const float* __restrict__ bias,
    short* __restrict__ xhi, short* __restrict__ xlo)
{
    __shared__ float ss[4][49];
    __shared__ int   isrc[4][49];
    const int tid = threadIdx.x;

    if (tid < 196) {
        const int p = tid / 49, k = tid - p * 49;
        const int pixg = blockIdx.x * 4 + p;
        const int b   = pixg >> 9;
        const int rem = pixg & 511;
        const int hp  = rem >> 5;
        const int wp  = rem & 31;
        float accy = OB[2 * k], accx = OB[2 * k + 1];
        const int di0 = (hp + 1) & 1, dj0 = (wp + 1) & 1;
        for (int di = di0; di < 7; di += 2) {
            const int yp = hp + di - 3;
            if ((unsigned)yp >= 16u) continue;
            const int ys = yp >> 1;
            for (int dj = dj0; dj < 7; dj += 2) {
                const int xp = wp + dj - 3;
                if ((unsigned)xp >= 32u) continue;
                const int xs = xp >> 1;
                const size_t o = ((size_t)((di * 7 + dj) * 256 + (b * 8 + ys) * 16 + xs)) * 98 + 2 * k;
                accy += (Zp[o] + Zp[o + 1229312]) + (Zp[o + 2458624] + Zp[o + 3687936]);
                accx += (Zp[o + 1] + Zp[o + 1229313]) + (Zp[o + 2458625] + Zp[o + 3687937]);
            }
        }
        d_bilin(accy, accx, hp, wp, b, k, 8, 16, 16, 32, ss[p][k], isrc[p][k]);
    }
    __syncthreads();

    const int f = tid & 63;
    const int p = tid >> 6;
    const int pixg = blockIdx.x * 4 + p;
    float acc = bias[f];
    #pragma unroll 7
    for (int k = 0; k < K49; ++k) {
        const size_t yo = ((size_t)k * 256 + isrc[p][k]) * 64 + f;
        const float yv = (Y[yo] + Y[yo + 802816]) + (Y[yo + 1605632] + Y[yo + 2408448]);
        acc = fmaf(ss[p][k], yv, acc);
    }
    const float v = fmaxf(acc, 0.f);
    const size_t o = (size_t)pixg * 64 + f;
    const short h = f2bf(v);
    xhi[o] = h;
    xlo[o] = f2bf(v - bf2f(h));
}

// ============ stages 2-3 GEMMs merged (offmfma + ygemm23): grid (gx, 53) ====
template<int C, int F>
__global__ __launch_bounds__(256) void k_gemms23(
    const short* __restrict__ Xbf, const short* __restrict__ OWf,
    const short* __restrict__ Wf,
    float* __restrict__ off, float* __restrict__ Y,
    const int H, const int W, const int Hp, const int Wp,
    const int M, const int nX)
{
    const int tid = threadIdx.x;
    const int wv = tid >> 6;
    const int l  = tid & 63;
    const int l15 = l & 15, l4 = l >> 4;
    const int by = blockIdx.y;

    if (by < 4) {
        const int cls = by;
        const int pi = cls >> 1, rho = cls & 1;
        const int NRc = pi ? 4 : 3, NCc = rho ? 4 : 3;
        const int T = NRc * NCc;
        int nkb, clsoff;
        if (C == 64) { nkb = T * 2; clsoff = cls == 0 ? 0 : cls == 1 ? 18 : cls == 2 ? 42 : 66; }
        else         { nkb = T;     clsoff = cls == 0 ? 0 : cls == 1 ? 9  : cls == 2 ? 21 : 33; }

        const int Wt16 = W >> 4;
        const int mt = blockIdx.x * 4 + wv;
        const int rloc = mt / Wt16, xt = mt - rloc * Wt16;
        const int b = rloc / H;
        const int ysp = rloc - b * H;

        f32x4 acc[7];
        #pragma unroll
        for (int nt = 0; nt < 7; ++nt) acc[nt] = (f32x4){0.f, 0.f, 0.f, 0.f};

        const bf16x8* Bbase = (const bf16x8*)OWf + ((size_t)clsoff * 7) * 64 + l4 * 16 + l15;

        for (int kb = 0; kb < nkb; ++kb) {
            int tl, c0;
            if (C == 64) { tl = kb >> 1; c0 = ((kb & 1) << 5) + l4 * 8; }
            else         { tl = kb;      c0 = l4 * 8; }
            int iy, ix;
            if (NCc == 4) { iy = tl >> 2; ix = tl & 3; }
            else          { iy = tl / 3;  ix = tl - iy * 3; }
            const int ys = ysp + iy - 1;
            const int xs = xt * 16 + l15 + ix - 1;
            bf16x8 ah = {0, 0, 0, 0, 0, 0, 0, 0};
            bf16x8 al = {0, 0, 0, 0, 0, 0, 0, 0};
            if ((unsigned)ys < (unsigned)H && (unsigned)xs < (unsigned)W) {
                const size_t a = ((size_t)(b * H + ys) * W + xs) * C + c0;
                ah = *(const bf16x8*)(Xbf + a);
                al = *(const bf16x8*)(Xbf + nX + a);
            }
            const bf16x8* Bb = Bbase + (size_t)kb * 7 * 64;
            #pragma unroll
            for (int nt = 0; nt < 7; ++nt) {
                const bf16x8 bf = Bb[nt * 64];
                acc[nt] = __builtin_amdgcn_mfma_f32_16x16x32_bf16(ah, bf, acc[nt], 0, 0, 0);
                acc[nt] = __builtin_amdgcn_mfma_f32_16x16x32_bf16(al, bf, acc[nt], 0, 0, 0);
            }
        }

        const int hp = 2 * ysp + pi;
        const int wpbase = (xt << 5) + rho;
        const int pixrow = (b * Hp + hp) * Wp + wpbase;
        #pragma unroll
        for (int nt = 0; nt < 7; ++nt) {
            const int oc = nt * 16 + l15;
            if (oc < 98) {
                #pragma unroll
                for (int r = 0; r < 4; ++r) {
                    const int m = l4 * 4 + r;
                    off[(size_t)(pixrow + 2 * m) * 98 + oc] = acc[nt][r];
                }
            }
        }
    } else {
        constexpr int KB = C / 32;
        constexpr int NT = F / 16;
        constexpr int PLANEFRAG = 49 * NT * KB * 64;
        const int d = by - 4;
        const int mtile = blockIdx.x * 4 + wv;
        const short* Arow = Xbf + (size_t)(mtile * 16 + l15) * C + l4 * 8;

        f32x4 acc[NT];
        #pragma unroll
        for (int nt = 0; nt < NT; ++nt) acc[nt] = (f32x4){0.f, 0.f, 0.f, 0.f};

        #pragma unroll
        for (int kb = 0; kb < KB; ++kb) {
            const bf16x8 ah = *(const bf16x8*)(Arow + kb * 32);
            const bf16x8 al = *(const bf16x8*)(Arow + nX + kb * 32);
            #pragma unroll
            for (int nt = 0; nt < NT; ++nt) {
                const size_t fi = ((size_t)(d * NT + nt) * KB + kb) * 64 + l4 * 16 + l15;
                const bf16x8 bh = ((const bf16x8*)Wf)[fi];
                const bf16x8 bl = ((const bf16x8*)Wf)[fi + PLANEFRAG];
                acc[nt] = __builtin_amdgcn_mfma_f32_16x16x32_bf16(ah, bh, acc[nt], 0, 0, 0);
                acc[nt] = __builtin_amdgcn_mfma_f32_16x16x32_bf16(ah, bl, acc[nt], 0, 0, 0);
                acc[nt] = __builtin_amdgcn_mfma_f32_16x16x32_bf16(al, bh, acc[nt], 0, 0, 0);
            }
        }

        const int m0 = mtile * 16 + l4 * 4;
        #pragma unroll
        for (int nt = 0; nt < NT; ++nt) {
            const int f = nt * 16 + l15;
            #pragma unroll
            for (int r = 0; r < 4; ++r)
                Y[((size_t)d * M + m0 + r) * F + f] = acc[nt][r];
        }
    }
}

// ============ stages 2-3 combine (fused sparams, optional Y4) ============
template<int F, bool DO_Y4>
__global__ __launch_bounds__(256) void k_combine23(
    const float* __restrict__ Y, const float* __restrict__ off,
    const float* __restrict__ OB, const float* __restrict__ bias,
    short* __restrict__ xhi, short* __restrict__ xlo,
    const float* __restrict__ w4, float* __restrict__ Y4,
    const int npix, const int nsrc,
    const int H, const int W, const int Hp, const int Wp)
{
    constexpr int PPB = 256 / F;
    __shared__ float ss[PPB][49];
    __shared__ int   isrc[PPB][49];
    __shared__ float xv[DO_Y4 ? PPB : 1][DO_Y4 ? 17 : 1];
    __shared__ float w4s[DO_Y4 ? 784 : 1];
    const int tid = threadIdx.x;
    const int HWp = Hp * Wp;

    if (DO_Y4) {
        for (int t = tid; t < 784; t += 256) w4s[t] = w4[t];
    }
    for (int t = tid; t < PPB * 49; t += 256) {
        const int p = t / 49, k = t - p * 49;
        const int pixg = blockIdx.x * PPB + p;
        const float accy = OB[2 * k]     + off[(size_t)pixg * 98 + 2 * k];
        const float accx = OB[2 * k + 1] + off[(size_t)pixg * 98 + 2 * k + 1];
        const int b = pixg / HWp;
        const int rem = pixg - b * HWp;
        const int hp = rem / Wp;
        const int wp = rem - hp * Wp;
        d_bilin(accy, accx, hp, wp, b, k, H, W, Hp, Wp, ss[p][k], isrc[p][k]);
    }
    __syncthreads();

    const int f = tid % F;
    const int p2 = tid / F;
    const int pixg2 = blockIdx.x * PPB + p2;
    float acc = bias[f];
    #pragma unroll 7
    for (int k = 0; k < K49; ++k)
        acc = fmaf(ss[p2][k], Y[((size_t)k * nsrc + isrc[p2][k]) * F + f], acc);
    const float v = fmaxf(acc, 0.f);
    const size_t o = (size_t)pixg2 * F + f;
    const short h = f2bf(v);
    xhi[o] = h;
    xlo[o] = f2bf(v - bf2f(h));

    if (DO_Y4) {
        xv[p2][f] = v;
        __syncthreads();
        for (int t = tid; t < PPB * 49; t += 256) {
            const int p = t / 49, k = t - p * 49;
            float d = 0.f;
            #pragma unroll
            for (int f2 = 0; f2 < 16; ++f2)
                d = fmaf(xv[p][f2], w4s[k * 16 + f2], d);
            Y4[(size_t)k * npix + blockIdx.x * PPB + p] = d;
        }
    }
}

// ============ stage 4 FUSED: implicit-GEMM offsets (LDS) + sparams + dconv ==
// grid (256, 4); block handles 64 pixels of one parity class.
__global__ __launch_bounds__(256) void k_stage4(
    const short* __restrict__ Xbf, const short* __restrict__ OWf,
    const float* __restrict__ Y4,       // [49][nsrc]
    const float* __restrict__ OB, const float* __restrict__ bias,
    float* __restrict__ out, const int nX)
{
    constexpr int C = 16, H = 64, W = 128, Hp = 128, Wp = 256;
    __shared__ float offs[64][98];
    __shared__ float OBs[98];

    const int tid = threadIdx.x;
    const int wv = tid >> 6;
    const int l  = tid & 63;
    const int l15 = l & 15, l4 = l >> 4;
    const int cls = blockIdx.y;
    const int pi = cls >> 1, rho = cls & 1;
    const int NRc = pi ? 4 : 3, NCc = rho ? 4 : 3;
    const int T = NRc * NCc;
    const int nkb = (T + 1) >> 1;
    const int clsoff = cls == 0 ? 0 : cls == 1 ? 5 : cls == 2 ? 11 : 17;

    if (tid < 98) OBs[tid] = OB[tid];

    // ---- phase 1: implicit-GEMM MFMA, acc -> LDS ----
    const int mt = blockIdx.x * 4 + wv;
    const int rloc = mt >> 3, xt = mt & 7;     // Wt16 = 8
    const int b = rloc / H;
    const int ysp = rloc - b * H;

    f32x4 acc[7];
    #pragma unroll
    for (int nt = 0; nt < 7; ++nt) acc[nt] = (f32x4){0.f, 0.f, 0.f, 0.f};

    const bf16x8* Bbase = (const bf16x8*)OWf + ((size_t)clsoff * 7) * 64 + l4 * 16 + l15;

    for (int kb = 0; kb < nkb; ++kb) {
        int tl = kb * 2 + (l4 >> 1);
        const int c0 = (l4 & 1) * 8;
        if (tl >= T) tl = T - 1;               // B is zero there; A clamp for bounds only
        int iy, ix;
        if (NCc == 4) { iy = tl >> 2; ix = tl & 3; }
        else          { iy = tl / 3;  ix = tl - iy * 3; }
        const int ys = ysp + iy - 1;
        const int xs = xt * 16 + l15 + ix - 1;
        bf16x8 ah = {0, 0, 0, 0, 0, 0, 0, 0};
        bf16x8 al = {0, 0, 0, 0, 0, 0, 0, 0};
        if ((unsigned)ys < (unsigned)H && (unsigned)xs < (unsigned)W) {
            const size_t a = ((size_t)(b * H + ys) * W + xs) * C + c0;
            ah = *(const bf16x8*)(Xbf + a);
            al = *(const bf16x8*)(Xbf + nX + a);
        }
        const bf16x8* Bb = Bbase + (size_t)kb * 7 * 64;
        #pragma unroll
        for (int nt = 0; nt < 7; ++nt) {
            const bf16x8 bf = Bb[nt * 64];
            acc[nt] = __builtin_amdgcn_mfma_f32_16x16x32_bf16(ah, bf, acc[nt], 0, 0, 0);
            acc[nt] = __builtin_amdgcn_mfma_f32_16x16x32_bf16(al, bf, acc[nt], 0, 0, 0);
        }
    }

    #pragma unroll
    for (int nt = 0; nt < 7; ++nt) {
        const int oc = nt * 16 + l15;
        if (oc < 98) {
            #pragma unroll
            for (int r = 0; r < 4; ++r)
                offs[wv * 16 + l4 * 4 + r][oc] = acc[nt][r];
        }
    }
    __syncthreads();

    // ---- phase 2: sparams + gather-combine (4 lanes per pixel) ----
    const int p  = tid >> 2;                   // 0..63 block-local pixel
    const int tq = tid & 3;
    const int t0 = (tq == 0) ? 0 : 13 + (tq - 1) * 12;
    const int t1 = t0 + ((tq == 0) ? 13 : 12);

    const int wv_p = p >> 4;
    const int m_p  = p & 15;
    const int mt_p = blockIdx.x * 4 + wv_p;
    const int rloc_p = mt_p >> 3, xt_p = mt_p & 7;
    const int b_p = rloc_p / H;
    const int ysp_p = rloc_p - b_p * H;
    const int hp = 2 * ysp_p + pi;
    const int wp = (xt_p << 5) + rho + 2 * m_p;
    const int pixg = (b_p * Hp + hp) * Wp + wp;

    float acc2 = 0.f;
    for (int k = t0; k < t1; ++k) {
        const float offy = offs[p][2 * k]     + OBs[2 * k];
        const float offx = offs[p][2 * k + 1] + OBs[2 * k + 1];
        float s; int src;
        d_bilin(offy, offx, hp, wp, b_p, k, H, W, Hp, Wp, s, src);
        acc2 = fmaf(s, Y4[(size_t)k * 16384 + src], acc2);
    }
    acc2 += __shfl_xor(acc2, 1);
    acc2 += __shfl_xor(acc2, 2);
    if (tq == 0) out[pixg] = acc2 + bias[0];
}

extern "C" void kernel_launch(void* const* d_in, const int* in_sizes, int n_in,
                              void* d_out, int out_size, void* d_ws, size_t ws_size,
                              hipStream_t stream) {
    const float* z   = (const float*)d_in[0];
    const float* dw  = (const float*)d_in[1];
    const float* db  = (const float*)d_in[2];
    const float* ow1 = (const float*)d_in[3];
    const float* ob1 = (const float*)d_in[4];
    const float* w1  = (const float*)d_in[5];
    const float* b1  = (const float*)d_in[6];
    const float* ow2 = (const float*)d_in[7];
    const float* ob2 = (const float*)d_in[8];
    const float* w2  = (const float*)d_in[9];
    const float* b2  = (const float*)d_in[10];
    const float* ow3 = (const float*)d_in[11];
    const float* ob3 = (const float*)d_in[12];
    const float* w3  = (const float*)d_in[13];
    const float* b3  = (const float*)d_in[14];
    const float* ow4 = (const float*)d_in[15];
    const float* ob4 = (const float*)d_in[16];
    const float* w4  = (const float*)d_in[17];
    const float* b4  = (const float*)d_in[18];

    // workspace layout: ~92 MB, no aliasing (ws_size = 256 MiB)
    float* ws   = (float*)d_ws;
    short* Xf   = (short*)ws;                    // 524,288 sh
    float* Zp   = ws + 262144;                   // 4 x 1,229,312 = 4,917,248
    float* Y1   = Zp + 4917248;                  // 4 x 802,816 = 3,211,264
    float* Y2   = Y1 + 3211264;                  // 1,605,632
    float* Y3   = Y2 + 1605632;                  // 3,211,264
    float* Y4   = Y3 + 3211264;                  // 802,816
    short* Xbf1 = (short*)(Y4 + 802816);         // 131,072 sh
    short* Xbf2 = Xbf1 + 131072;                 // 262,144 sh
    short* Xbf3 = Xbf2 + 262144;                 // 524,288 sh
    float* off2 = (float*)(Xbf3 + 524288);       // 401,408
    float* off3 = off2 + 401408;                 // 1,605,632
    short* OWbf = (short*)(off3 + 1605632);      // 5,619,712 sh
    short* W1f  = OWbf + 5619712;                // 6,422,528 sh
    short* OWf2 = W1f + 6422528;                 // 351,232 sh
    short* W2f  = OWf2 + 351232;                 // 200,704 sh
    short* OWf3 = W2f + 200704;                  // 175,616 sh
    short* W3f  = OWf3 + 175616;                 // 50,176 sh
    short* OWf4 = W3f + 50176;                   // 89,600 sh

    float* out = (float*)d_out;

    // 1) dense+cvt AND all weight packing (independent, one launch)
    k_prep<<<7294, 256, 0, stream>>>(z, dw, db, Xf, ow1, w1, ow2, w2, ow3, w3, ow4,
                                     OWbf, W1f, OWf2, W2f, OWf3, W3f, OWf4);

    // 2) stage-1 GEMMs (offset + Y; K-split x4, N-split x2, compile-time NT)
    k_gemms1<<<3136, 256, 0, stream>>>(Xf, OWbf, W1f, Zp, Y1);

    // 3) stage-1 combine (fused sparams_z1, sums 4 partials) -> Xbf1
    k_combine1<<<256, 256, 0, stream>>>(Y1, Zp, ob1, b1, Xbf1, Xbf1 + 65536);

    // 4) stage-2 GEMMs (offmfma + ygemm, merged)
    k_gemms23<64, 32><<<dim3(16, 53), 256, 0, stream>>>(
        Xbf1, OWf2, W2f, off2, Y2, 16, 32, 32, 64, 1024, 65536);

    // 5) stage-2 combine -> Xbf2
    k_combine23<32, false><<<512, 256, 0, stream>>>(
        Y2, off2, ob2, b2, Xbf2, Xbf2 + 131072, nullptr, nullptr, 4096, 1024, 16, 32, 32, 64);

    // 6) stage-3 GEMMs
    k_gemms23<32, 16><<<dim3(64, 53), 256, 0, stream>>>(
        Xbf2, OWf3, W3f, off3, Y3, 32, 64, 64, 128, 4096, 131072);

    // 7) stage-3 combine + Y4 -> Xbf3, Y4
    k_combine23<16, true><<<1024, 256, 0, stream>>>(
        Y3, off3, ob3, b3, Xbf3, Xbf3 + 262144, w4, Y4, 16384, 4096, 32, 64, 64, 128);

    // 8) stage-4 fused: offsets (MFMA->LDS) + sparams + dconv -> out
    k_stage4<<<dim3(256, 4), 256, 0, stream>>>(Xbf3, OWf4, Y4, ob4, b4, out, 262144);
}

// Round 18
// 137.320 us; speedup vs baseline: 1.0937x; 1.0025x over previous
//
#include <hip/hip_runtime.h>
#include <hip/hip_bf16.h>

#define K49 49

typedef short bf16x8 __attribute__((ext_vector_type(8)));
typedef float f32x4 __attribute__((ext_vector_type(4)));

__device__ __forceinline__ short f2bf(float x) {
    __hip_bfloat16 h = __float2bfloat16(x);
    return __builtin_bit_cast(short, h);
}
__device__ __forceinline__ float bf2f(short s) {
    unsigned u = ((unsigned)(unsigned short)s) << 16;
    return __builtin_bit_cast(float, u);
}

// ==================== weight packing (device fns) ====================
__device__ __forceinline__ void d_pack_ow1(
    const int gid, const float* __restrict__ OW, short* __restrict__ OWbf)
{
    const int ni = gid & 15;
    int t = gid >> 4;
    const int kg = t & 3;  t >>= 2;
    const int kb = t & 31; t >>= 5;
    const int nt = t % 7;
    const int d  = t / 7;
    const int oc = nt * 16 + ni;
    short h[8];
    if (oc < 98) {
        const int c0 = kb * 32 + kg * 8;
        #pragma unroll
        for (int j = 0; j < 8; ++j)
            h[j] = f2bf(OW[((size_t)d * 1024 + c0 + j) * 98 + oc]);
    } else {
        #pragma unroll
        for (int j = 0; j < 8; ++j) h[j] = 0;
    }
    *(bf16x8*)(OWbf + (size_t)gid * 8) = *(bf16x8*)h;
}

template<int C, int F>
__device__ __forceinline__ void d_pack_w(
    const int gid, const float* __restrict__ Wt, short* __restrict__ Wf)
{
    constexpr int KB = C / 32;
    constexpr int NT = F / 16;
    constexpr int PLANE = 49 * NT * KB * 4 * 16 * 8;   // shorts
    const int ni = gid & 15;
    int t = gid >> 4;
    const int kg = t & 3; t >>= 2;
    const int kb = t % KB; t /= KB;
    const int nt = t % NT;
    const int d  = t / NT;
    const int f = nt * 16 + ni;
    const int c0 = kb * 32 + kg * 8;
    short hi[8], lo[8];
    #pragma unroll
    for (int j = 0; j < 8; ++j) {
        const float v = Wt[((size_t)d * C + c0 + j) * F + f];
        hi[j] = f2bf(v);
        lo[j] = f2bf(v - bf2f(hi[j]));
    }
    *(bf16x8*)(Wf + (size_t)gid * 8) = *(bf16x8*)hi;
    *(bf16x8*)(Wf + PLANE + (size_t)gid * 8) = *(bf16x8*)lo;
}

template<int C>
__device__ __forceinline__ void d_pack_owf(
    const int gid, const float* __restrict__ OW, short* __restrict__ OWf)
{
    const int j = gid & 7;
    int t = gid >> 3;
    const int fi = t & 63; t >>= 6;
    const int nt = t % 7;
    const int kbg = t / 7;
    const int ni = fi & 15, kg = fi >> 4;

    int cum1, cum2, cum3;
    if (C == 64)      { cum1 = 18; cum2 = 42; cum3 = 66; }
    else if (C == 32) { cum1 = 9;  cum2 = 21; cum3 = 33; }
    else              { cum1 = 5;  cum2 = 11; cum3 = 17; }
    int cls, kb0;
    if (kbg < cum1)      { cls = 0; kb0 = 0; }
    else if (kbg < cum2) { cls = 1; kb0 = cum1; }
    else if (kbg < cum3) { cls = 2; kb0 = cum2; }
    else                 { cls = 3; kb0 = cum3; }
    const int kbl = kbg - kb0;
    const int pi = cls >> 1, rho = cls & 1;
    const int NRc = pi ? 4 : 3, NCc = rho ? 4 : 3;
    const int T = NRc * NCc;

    const int k = kbl * 32 + kg * 8 + j;
    const int tl = k / C, c = k - tl * C;
    const int oc = nt * 16 + ni;
    float v = 0.f;
    if (tl < T && oc < 98) {
        const int iy = tl / NCc, ix = tl - iy * NCc;
        const int d = (1 - pi + 2 * iy) * 7 + (1 - rho + 2 * ix);
        v = OW[((size_t)d * C + c) * 98 + oc];
    }
    OWf[gid] = f2bf(v);
}

// ==================== mega prep kernel: dense+cvt AND all weight packs =====
// Xf layout (bf16): [plane(2)][mtile(16)][kb(32)][kg(4)][mi(16)][8]
__global__ __launch_bounds__(256) void k_prep(
    const float* __restrict__ z, const float* __restrict__ Wd,
    const float* __restrict__ bd, short* __restrict__ Xf,
    const float* __restrict__ ow1, const float* __restrict__ w1,
    const float* __restrict__ ow2, const float* __restrict__ w2,
    const float* __restrict__ ow3, const float* __restrict__ w3,
    const float* __restrict__ ow4,
    short* OWbf, short* W1f, short* OWf2, short* W2f,
    short* OWf3, short* W3f, short* OWf4)
{
    const int bid0 = blockIdx.x;
    const int tid = threadIdx.x;
    __shared__ float zs[256];
    if (bid0 < 512) {
        const int D = 131072;
        zs[tid] = z[tid];
        __syncthreads();
        const int n = bid0 * 256 + tid;
        const float bb = bd[n];
        float a0 = bb, a1 = bb;
        #pragma unroll 8
        for (int kk = 0; kk < 128; ++kk) {
            const float w = Wd[kk * D + n];
            a0 = fmaf(zs[kk], w, a0);
            a1 = fmaf(zs[128 + kk], w, a1);
        }
        a0 = fmaxf(a0, 0.f);
        a1 = fmaxf(a1, 0.f);
        const int c = n & 1023;
        const int m0 = n >> 10;
        const int kb = c >> 5, kg = (c >> 3) & 3, j = c & 7;
        const size_t base = ((size_t)kb * 4 + kg) * 16 * 8 + j;
        {
            const size_t dst = ((size_t)(m0 >> 4) * 2048) * 8 + base + (size_t)(m0 & 15) * 8;
            const short h = f2bf(a0);
            Xf[dst] = h;
            Xf[262144 + dst] = f2bf(a0 - bf2f(h));
        }
        {
            const int m1 = m0 + 128;
            const size_t dst = ((size_t)(m1 >> 4) * 2048) * 8 + base + (size_t)(m1 & 15) * 8;
            const short h = f2bf(a1);
            Xf[dst] = h;
            Xf[262144 + dst] = f2bf(a1 - bf2f(h));
        }
        return;
    }
    const int bid = bid0 - 512;
    if (bid < 2744)      d_pack_ow1((bid) * 256 + tid, ow1, OWbf);
    else if (bid < 4312) d_pack_w<1024, 64>((bid - 2744) * 256 + tid, w1, W1f);
    else if (bid < 5684) d_pack_owf<64>((bid - 4312) * 256 + tid, ow2, OWf2);
    else if (bid < 5733) d_pack_w<64, 32>((bid - 5684) * 256 + tid, w2, W2f);
    else if (bid < 6419) d_pack_owf<32>((bid - 5733) * 256 + tid, ow3, OWf3);
    else if (bid < 6432) { const int g = (bid - 6419) * 256 + tid; if (g < 3136) d_pack_w<32, 16>(g, w3, W3f); }
    else                 d_pack_owf<16>((bid - 6432) * 256 + tid, ow4, OWf4);
}

// ============ Z-branch body, compile-time NT so everything unrolls =========
template<int NT>
__device__ __forceinline__ void d_zpart(
    const bf16x8* __restrict__ Ah, const bf16x8* __restrict__ Al,
    const bf16x8* __restrict__ Bb, float* __restrict__ Zo,
    const int d, const int m0, const int l15, const int nt0, const int kb0)
{
    f32x4 acc[NT];
    #pragma unroll
    for (int nt = 0; nt < NT; ++nt) acc[nt] = (f32x4){0.f, 0.f, 0.f, 0.f};
    #pragma unroll
    for (int i = 0; i < 8; ++i) {
        const int kb = kb0 + i;
        const bf16x8 ah = Ah[kb * 64];
        const bf16x8 al = Al[kb * 64];
        #pragma unroll
        for (int nt = 0; nt < NT; ++nt) {
            const bf16x8 b = Bb[(size_t)nt * 2048 + kb * 64];
            acc[nt] = __builtin_amdgcn_mfma_f32_16x16x32_bf16(ah, b, acc[nt], 0, 0, 0);
            acc[nt] = __builtin_amdgcn_mfma_f32_16x16x32_bf16(al, b, acc[nt], 0, 0, 0);
        }
    }
    #pragma unroll
    for (int nt = 0; nt < NT; ++nt) {
        const int oc = (nt0 + nt) * 16 + l15;
        if (oc < 98) {
            #pragma unroll
            for (int r = 0; r < 4; ++r)
                Zo[((size_t)d * 256 + m0 + r) * 98 + oc] = acc[nt][r];
        }
    }
}

// ============ stage-1 GEMMs, K-split x4 + N-split x2: grid 3136 =====
// Zp partial: [ks][49][256][98]; Y1 partial: [ks][49][256][64]
__global__ __launch_bounds__(256) void k_gemms1(
    const short* __restrict__ Xf, const short* __restrict__ OWbf,
    const short* __restrict__ W1f,
    float* __restrict__ Zp, float* __restrict__ Y1)
{
    const int tid = threadIdx.x;
    const int wv = tid >> 6;
    const int l  = tid & 63;
    const int l15 = l & 15, l4 = l >> 4;

    // XCD-aware: 4 M-sibling blocks (same B-slice) consecutive -> same XCD
    const int bid = blockIdx.x;                  // 0..3135
    const int work = (bid & 7) * 392 + (bid >> 3);
    const int x    = work & 3;
    const int rest = work >> 2;                  // 0..783
    const int ks   = rest / 196;
    const int by   = rest - ks * 196;

    const int mtile = x * 4 + wv;
    const int kb0 = ks * 8;
    const int lofs = l4 * 16 + l15;

    const bf16x8* Ah = (const bf16x8*)Xf + (size_t)mtile * 2048 + lofs;
    const bf16x8* Al = Ah + 32768;
    const int m0 = mtile * 16 + l4 * 4;

    if (by < 98) {
        const int d   = by >> 1;
        const int nth = by & 1;
        float* Zo = Zp + (size_t)ks * 1229312;
        if (nth == 0) {
            const bf16x8* Bb = (const bf16x8*)OWbf + (size_t)(d * 7) * 2048 + lofs;
            d_zpart<4>(Ah, Al, Bb, Zo, d, m0, l15, 0, kb0);
        } else {
            const bf16x8* Bb = (const bf16x8*)OWbf + (size_t)(d * 7 + 4) * 2048 + lofs;
            d_zpart<3>(Ah, Al, Bb, Zo, d, m0, l15, 4, kb0);
        }
    } else {
        const int dd  = by - 98;
        const int d   = dd >> 1;
        const int nt0 = (dd & 1) * 2;
        const bf16x8* Bh = (const bf16x8*)W1f + (size_t)(d * 4 + nt0) * 2048 + lofs;
        const bf16x8* Bl = Bh + 401408;
        f32x4 acc[2];
        #pragma unroll
        for (int nt = 0; nt < 2; ++nt) acc[nt] = (f32x4){0.f, 0.f, 0.f, 0.f};
        #pragma unroll
        for (int i = 0; i < 8; ++i) {
            const int kb = kb0 + i;
            const bf16x8 ah = Ah[kb * 64];
            const bf16x8 al = Al[kb * 64];
            #pragma unroll
            for (int nt = 0; nt < 2; ++nt) {
                const bf16x8 bh = Bh[nt * 2048 + kb * 64];
                const bf16x8 bl = Bl[nt * 2048 + kb * 64];
                acc[nt] = __builtin_amdgcn_mfma_f32_16x16x32_bf16(ah, bh, acc[nt], 0, 0, 0);
                acc[nt] = __builtin_amdgcn_mfma_f32_16x16x32_bf16(ah, bl, acc[nt], 0, 0, 0);
                acc[nt] = __builtin_amdgcn_mfma_f32_16x16x32_bf16(al, bh, acc[nt], 0, 0, 0);
            }
        }
        float* Yo = Y1 + (size_t)ks * 802816;
        #pragma unroll
        for (int nt = 0; nt < 2; ++nt) {
            const int f = (nt0 + nt) * 16 + l15;
            #pragma unroll
            for (int r = 0; r < 4; ++r)
                Yo[((size_t)d * 256 + m0 + r) * 64 + f] = acc[nt][r];
        }
    }
}

// ============ sparams device fn ============
__device__ __forceinline__ void d_bilin(
    const float accy, const float accx, const int hp, const int wp,
    const int b, const int k, const int H, const int W, const int Hp, const int Wp,
    float& s_out, int& src_out)
{
    const float y = (float)(hp + (k / 7) - 3) + accy;
    const float x = (float)(wp + (k % 7) - 3) + accx;
    const float fy0 = floorf(y), fx0 = floorf(x);
    const int iy0 = (int)fy0, ix0 = (int)fx0;
    const float wy1 = y - fy0, wx1 = x - fx0;
    int ye, xe; float wy, wx;
    if (iy0 & 1) { ye = iy0 + 1; wy = wy1; } else { ye = iy0; wy = 1.f - wy1; }
    if (ix0 & 1) { xe = ix0 + 1; wx = wx1; } else { xe = ix0; wx = 1.f - wx1; }
    float s = wy * wx;
    int src = 0;
    if (ye >= 0 && ye < Hp && xe >= 0 && xe < Wp)
        src = (b * H + (ye >> 1)) * W + (xe >> 1);
    else
        s = 0.f;
    s_out = s;
    src_out = src;
}

// ============ stage-1 combine (fused sparams_z1, 4 partials) ============
__global__ __launch_bounds__(256) void k_combine1(
    const float* __restrict__ Y, const float* __restrict__ Zp,
    const float* __restrict__ OB, const float* __restrict__ bias,
    short* __restrict__ xhi, short* __restrict__ xlo)
{
    __shared__ float ss[4][49];
    __shared__ int   isrc[4][49];
    const int tid = threadIdx.x;

    if (tid < 196) {
        const int p = tid / 49, k = tid - p * 49;
        const int pixg = blockIdx.x * 4 + p;
        const int b   = pixg >> 9;
        const int rem = pixg & 511;
        const int hp  = rem >> 5;
        const int wp  = rem & 31;
        float accy = OB[2 * k], accx = OB[2 * k + 1];
        const int di0 = (hp + 1) & 1, dj0 = (wp + 1) & 1;
        for (int di = di0; di < 7; di += 2) {
            const int yp = hp + di - 3;
            if ((unsigned)yp >= 16u) continue;
            const int ys = yp >> 1;
            for (int dj = dj0; dj < 7; dj += 2) {
                const int xp = wp + dj - 3;
                if ((unsigned)xp >= 32u) continue;
                const int xs = xp >> 1;
                const size_t o = ((size_t)((di * 7 + dj) * 256 + (b * 8 + ys) * 16 + xs)) * 98 + 2 * k;
                accy += (Zp[o] + Zp[o + 1229312]) + (Zp[o + 2458624] + Zp[o + 3687936]);
                accx += (Zp[o + 1] + Zp[o + 1229313]) + (Zp[o + 2458625] + Zp[o + 3687937]);
            }
        }
        d_bilin(accy, accx, hp, wp, b, k, 8, 16, 16, 32, ss[p][k], isrc[p][k]);
    }
    __syncthreads();

    const int f = tid & 63;
    const int p = tid >> 6;
    const int pixg = blockIdx.x * 4 + p;
    float acc = bias[f];
    #pragma unroll 7
    for (int k = 0; k < K49; ++k) {
        const size_t yo = ((size_t)k * 256 + isrc[p][k]) * 64 + f;
        const float yv = (Y[yo] + Y[yo + 802816]) + (Y[yo + 1605632] + Y[yo + 2408448]);
        acc = fmaf(ss[p][k], yv, acc);
    }
    const float v = fmaxf(acc, 0.f);
    const size_t o = (size_t)pixg * 64 + f;
    const short h = f2bf(v);
    xhi[o] = h;
    xlo[o] = f2bf(v - bf2f(h));
}

// ============ stages 2-3 GEMMs merged (offmfma + ygemm23): grid (gx, 53) ====
template<int C, int F>
__global__ __launch_bounds__(256) void k_gemms23(
    const short* __restrict__ Xbf, const short* __restrict__ OWf,
    const short* __restrict__ Wf,
    float* __restrict__ off, float* __restrict__ Y,
    const int H, const int W, const int Hp, const int Wp,
    const int M, const int nX)
{
    const int tid = threadIdx.x;
    const int wv = tid >> 6;
    const int l  = tid & 63;
    const int l15 = l & 15, l4 = l >> 4;
    const int by = blockIdx.y;

    if (by < 4) {
        const int cls = by;
        const int pi = cls >> 1, rho = cls & 1;
        const int NRc = pi ? 4 : 3, NCc = rho ? 4 : 3;
        const int T = NRc * NCc;
        int nkb, clsoff;
        if (C == 64) { nkb = T * 2; clsoff = cls == 0 ? 0 : cls == 1 ? 18 : cls == 2 ? 42 : 66; }
        else         { nkb = T;     clsoff = cls == 0 ? 0 : cls == 1 ? 9  : cls == 2 ? 21 : 33; }

        const int Wt16 = W >> 4;
        const int mt = blockIdx.x * 4 + wv;
        const int rloc = mt / Wt16, xt = mt - rloc * Wt16;
        const int b = rloc / H;
        const int ysp = rloc - b * H;

        f32x4 acc[7];
        #pragma unroll
        for (int nt = 0; nt < 7; ++nt) acc[nt] = (f32x4){0.f, 0.f, 0.f, 0.f};

        const bf16x8* Bbase = (const bf16x8*)OWf + ((size_t)clsoff * 7) * 64 + l4 * 16 + l15;

        for (int kb = 0; kb < nkb; ++kb) {
            int tl, c0;
            if (C == 64) { tl = kb >> 1; c0 = ((kb & 1) << 5) + l4 * 8; }
            else         { tl = kb;      c0 = l4 * 8; }
            int iy, ix;
            if (NCc == 4) { iy = tl >> 2; ix = tl & 3; }
            else          { iy = tl / 3;  ix = tl - iy * 3; }
            const int ys = ysp + iy - 1;
            const int xs = xt * 16 + l15 + ix - 1;
            bf16x8 ah = {0, 0, 0, 0, 0, 0, 0, 0};
            bf16x8 al = {0, 0, 0, 0, 0, 0, 0, 0};
            if ((unsigned)ys < (unsigned)H && (unsigned)xs < (unsigned)W) {
                const size_t a = ((size_t)(b * H + ys) * W + xs) * C + c0;
                ah = *(const bf16x8*)(Xbf + a);
                al = *(const bf16x8*)(Xbf + nX + a);
            }
            const bf16x8* Bb = Bbase + (size_t)kb * 7 * 64;
            #pragma unroll
            for (int nt = 0; nt < 7; ++nt) {
                const bf16x8 bf = Bb[nt * 64];
                acc[nt] = __builtin_amdgcn_mfma_f32_16x16x32_bf16(ah, bf, acc[nt], 0, 0, 0);
                acc[nt] = __builtin_amdgcn_mfma_f32_16x16x32_bf16(al, bf, acc[nt], 0, 0, 0);
            }
        }

        const int hp = 2 * ysp + pi;
        const int wpbase = (xt << 5) + rho;
        const int pixrow = (b * Hp + hp) * Wp + wpbase;
        #pragma unroll
        for (int nt = 0; nt < 7; ++nt) {
            const int oc = nt * 16 + l15;
            if (oc < 98) {
                #pragma unroll
                for (int r = 0; r < 4; ++r) {
                    const int m = l4 * 4 + r;
                    off[(size_t)(pixrow + 2 * m) * 98 + oc] = acc[nt][r];
                }
            }
        }
    } else {
        constexpr int KB = C / 32;
        constexpr int NT = F / 16;
        constexpr int PLANEFRAG = 49 * NT * KB * 64;
        const int d = by - 4;
        const int mtile = blockIdx.x * 4 + wv;
        const short* Arow = Xbf + (size_t)(mtile * 16 + l15) * C + l4 * 8;

        f32x4 acc[NT];
        #pragma unroll
        for (int nt = 0; nt < NT; ++nt) acc[nt] = (f32x4){0.f, 0.f, 0.f, 0.f};

        #pragma unroll
        for (int kb = 0; kb < KB; ++kb) {
            const bf16x8 ah = *(const bf16x8*)(Arow + kb * 32);
            const bf16x8 al = *(const bf16x8*)(Arow + nX + kb * 32);
            #pragma unroll
            for (int nt = 0; nt < NT; ++nt) {
                const size_t fi = ((size_t)(d * NT + nt) * KB + kb) * 64 + l4 * 16 + l15;
                const bf16x8 bh = ((const bf16x8*)Wf)[fi];
                const bf16x8 bl = ((const bf16x8*)Wf)[fi + PLANEFRAG];
                acc[nt] = __builtin_amdgcn_mfma_f32_16x16x32_bf16(ah, bh, acc[nt], 0, 0, 0);
                acc[nt] = __builtin_amdgcn_mfma_f32_16x16x32_bf16(ah, bl, acc[nt], 0, 0, 0);
                acc[nt] = __builtin_amdgcn_mfma_f32_16x16x32_bf16(al, bh, acc[nt], 0, 0, 0);
            }
        }

        const int m0 = mtile * 16 + l4 * 4;
        #pragma unroll
        for (int nt = 0; nt < NT; ++nt) {
            const int f = nt * 16 + l15;
            #pragma unroll
            for (int r = 0; r < 4; ++r)
                Y[((size_t)d * M + m0 + r) * F + f] = acc[nt][r];
        }
    }
}

// ============ stages 2-3 combine (fused sparams, optional Y4) ============
template<int F, bool DO_Y4>
__global__ __launch_bounds__(256) void k_combine23(
    const float* __restrict__ Y, const float* __restrict__ off,
    const float* __restrict__ OB, const float* __restrict__ bias,
    short* __restrict__ xhi, short* __restrict__ xlo,
    const float* __restrict__ w4, float* __restrict__ Y4,
    const int npix, const int nsrc,
    const int H, const int W, const int Hp, const int Wp)
{
    constexpr int PPB = 256 / F;
    __shared__ float ss[PPB][49];
    __shared__ int   isrc[PPB][49];
    __shared__ float xv[DO_Y4 ? PPB : 1][DO_Y4 ? 17 : 1];
    __shared__ float w4s[DO_Y4 ? 784 : 1];
    const int tid = threadIdx.x;
    const int HWp = Hp * Wp;

    if (DO_Y4) {
        for (int t = tid; t < 784; t += 256) w4s[t] = w4[t];
    }
    for (int t = tid; t < PPB * 49; t += 256) {
        const int p = t / 49, k = t - p * 49;
        const int pixg = blockIdx.x * PPB + p;
        const float accy = OB[2 * k]     + off[(size_t)pixg * 98 + 2 * k];
        const float accx = OB[2 * k + 1] + off[(size_t)pixg * 98 + 2 * k + 1];
        const int b = pixg / HWp;
        const int rem = pixg - b * HWp;
        const int hp = rem / Wp;
        const int wp = rem - hp * Wp;
        d_bilin(accy, accx, hp, wp, b, k, H, W, Hp, Wp, ss[p][k], isrc[p][k]);
    }
    __syncthreads();

    const int f = tid % F;
    const int p2 = tid / F;
    const int pixg2 = blockIdx.x * PPB + p2;
    float acc = bias[f];
    #pragma unroll 7
    for (int k = 0; k < K49; ++k)
        acc = fmaf(ss[p2][k], Y[((size_t)k * nsrc + isrc[p2][k]) * F + f], acc);
    const float v = fmaxf(acc, 0.f);
    const size_t o = (size_t)pixg2 * F + f;
    const short h = f2bf(v);
    xhi[o] = h;
    xlo[o] = f2bf(v - bf2f(h));

    if (DO_Y4) {
        xv[p2][f] = v;
        __syncthreads();
        for (int t = tid; t < PPB * 49; t += 256) {
            const int p = t / 49, k = t - p * 49;
            float d = 0.f;
            #pragma unroll
            for (int f2 = 0; f2 < 16; ++f2)
                d = fmaf(xv[p][f2], w4s[k * 16 + f2], d);
            Y4[(size_t)k * npix + blockIdx.x * PPB + p] = d;
        }
    }
}

// ============ stage 4 FUSED: implicit-GEMM offsets (LDS) + sparams + dconv ==
// grid (256, 4); block handles 64 pixels of one parity class.
__global__ __launch_bounds__(256) void k_stage4(
    const short* __restrict__ Xbf, const short* __restrict__ OWf,
    const float* __restrict__ Y4,       // [49][nsrc]
    const float* __restrict__ OB, const float* __restrict__ bias,
    float* __restrict__ out, const int nX)
{
    constexpr int C = 16, H = 64, W = 128, Hp = 128, Wp = 256;
    __shared__ float offs[64][98];
    __shared__ float OBs[98];

    const int tid = threadIdx.x;
    const int wv = tid >> 6;
    const int l  = tid & 63;
    const int l15 = l & 15, l4 = l >> 4;
    const int cls = blockIdx.y;
    const int pi = cls >> 1, rho = cls & 1;
    const int NRc = pi ? 4 : 3, NCc = rho ? 4 : 3;
    const int T = NRc * NCc;
    const int nkb = (T + 1) >> 1;
    const int clsoff = cls == 0 ? 0 : cls == 1 ? 5 : cls == 2 ? 11 : 17;

    if (tid < 98) OBs[tid] = OB[tid];

    // ---- phase 1: implicit-GEMM MFMA, acc -> LDS ----
    const int mt = blockIdx.x * 4 + wv;
    const int rloc = mt >> 3, xt = mt & 7;     // Wt16 = 8
    const int b = rloc / H;
    const int ysp = rloc - b * H;

    f32x4 acc[7];
    #pragma unroll
    for (int nt = 0; nt < 7; ++nt) acc[nt] = (f32x4){0.f, 0.f, 0.f, 0.f};

    const bf16x8* Bbase = (const bf16x8*)OWf + ((size_t)clsoff * 7) * 64 + l4 * 16 + l15;

    for (int kb = 0; kb < nkb; ++kb) {
        int tl = kb * 2 + (l4 >> 1);
        const int c0 = (l4 & 1) * 8;
        if (tl >= T) tl = T - 1;               // B is zero there; A clamp for bounds only
        int iy, ix;
        if (NCc == 4) { iy = tl >> 2; ix = tl & 3; }
        else          { iy = tl / 3;  ix = tl - iy * 3; }
        const int ys = ysp + iy - 1;
        const int xs = xt * 16 + l15 + ix - 1;
        bf16x8 ah = {0, 0, 0, 0, 0, 0, 0, 0};
        bf16x8 al = {0, 0, 0, 0, 0, 0, 0, 0};
        if ((unsigned)ys < (unsigned)H && (unsigned)xs < (unsigned)W) {
            const size_t a = ((size_t)(b * H + ys) * W + xs) * C + c0;
            ah = *(const bf16x8*)(Xbf + a);
            al = *(const bf16x8*)(Xbf + nX + a);
        }
        const bf16x8* Bb = Bbase + (size_t)kb * 7 * 64;
        #pragma unroll
        for (int nt = 0; nt < 7; ++nt) {
            const bf16x8 bf = Bb[nt * 64];
            acc[nt] = __builtin_amdgcn_mfma_f32_16x16x32_bf16(ah, bf, acc[nt], 0, 0, 0);
            acc[nt] = __builtin_amdgcn_mfma_f32_16x16x32_bf16(al, bf, acc[nt], 0, 0, 0);
        }
    }

    #pragma unroll
    for (int nt = 0; nt < 7; ++nt) {
        const int oc = nt * 16 + l15;
        if (oc < 98) {
            #pragma unroll
            for (int r = 0; r < 4; ++r)
                offs[wv * 16 + l4 * 4 + r][oc] = acc[nt][r];
        }
    }
    __syncthreads();

    // ---- phase 2: sparams + gather-combine (4 lanes per pixel) ----
    const int p  = tid >> 2;                   // 0..63 block-local pixel
    const int tq = tid & 3;
    const int t0 = (tq == 0) ? 0 : 13 + (tq - 1) * 12;
    const int t1 = t0 + ((tq == 0) ? 13 : 12);

    const int wv_p = p >> 4;
    const int m_p  = p & 15;
    const int mt_p = blockIdx.x * 4 + wv_p;
    const int rloc_p = mt_p >> 3, xt_p = mt_p & 7;
    const int b_p = rloc_p / H;
    const int ysp_p = rloc_p - b_p * H;
    const int hp = 2 * ysp_p + pi;
    const int wp = (xt_p << 5) + rho + 2 * m_p;
    const int pixg = (b_p * Hp + hp) * Wp + wp;

    float acc2 = 0.f;
    for (int k = t0; k < t1; ++k) {
        const float offy = offs[p][2 * k]     + OBs[2 * k];
        const float offx = offs[p][2 * k + 1] + OBs[2 * k + 1];
        float s; int src;
        d_bilin(offy, offx, hp, wp, b_p, k, H, W, Hp, Wp, s, src);
        acc2 = fmaf(s, Y4[(size_t)k * 16384 + src], acc2);
    }
    acc2 += __shfl_xor(acc2, 1);
    acc2 += __shfl_xor(acc2, 2);
    if (tq == 0) out[pixg] = acc2 + bias[0];
}

extern "C" void kernel_launch(void* const* d_in, const int* in_sizes, int n_in,
                              void* d_out, int out_size, void* d_ws, size_t ws_size,
                              hipStream_t stream) {
    const float* z   = (const float*)d_in[0];
    const float* dw  = (const float*)d_in[1];
    const float* db  = (const float*)d_in[2];
    const float* ow1 = (const float*)d_in[3];
    const float* ob1 = (const float*)d_in[4];
    const float* w1  = (const float*)d_in[5];
    const float* b1  = (const float*)d_in[6];
    const float* ow2 = (const float*)d_in[7];
    const float* ob2 = (const float*)d_in[8];
    const float* w2  = (const float*)d_in[9];
    const float* b2  = (const float*)d_in[10];
    const float* ow3 = (const float*)d_in[11];
    const float* ob3 = (const float*)d_in[12];
    const float* w3  = (const float*)d_in[13];
    const float* b3  = (const float*)d_in[14];
    const float* ow4 = (const float*)d_in[15];
    const float* ob4 = (const float*)d_in[16];
    const float* w4  = (const float*)d_in[17];
    const float* b4  = (const float*)d_in[18];

    // workspace layout: ~92 MB, no aliasing (ws_size = 256 MiB)
    float* ws   = (float*)d_ws;
    short* Xf   = (short*)ws;                    // 524,288 sh
    float* Zp   = ws + 262144;                   // 4 x 1,229,312 = 4,917,248
    float* Y1   = Zp + 4917248;                  // 4 x 802,816 = 3,211,264
    float* Y2   = Y1 + 3211264;                  // 1,605,632
    float* Y3   = Y2 + 1605632;                  // 3,211,264
    float* Y4   = Y3 + 3211264;                  // 802,816
    short* Xbf1 = (short*)(Y4 + 802816);         // 131,072 sh
    short* Xbf2 = Xbf1 + 131072;                 // 262,144 sh
    short* Xbf3 = Xbf2 + 262144;                 // 524,288 sh
    float* off2 = (float*)(Xbf3 + 524288);       // 401,408
    float* off3 = off2 + 401408;                 // 1,605,632
    short* OWbf = (short*)(off3 + 1605632);      // 5,619,712 sh
    short* W1f  = OWbf + 5619712;                // 6,422,528 sh
    short* OWf2 = W1f + 6422528;                 // 351,232 sh
    short* W2f  = OWf2 + 351232;                 // 200,704 sh
    short* OWf3 = W2f + 200704;                  // 175,616 sh
    short* W3f  = OWf3 + 175616;                 // 50,176 sh
    short* OWf4 = W3f + 50176;                   // 89,600 sh

    float* out = (float*)d_out;

    // 1) dense+cvt AND all weight packing (independent, one launch)
    k_prep<<<7294, 256, 0, stream>>>(z, dw, db, Xf, ow1, w1, ow2, w2, ow3, w3, ow4,
                                     OWbf, W1f, OWf2, W2f, OWf3, W3f, OWf4);

    // 2) stage-1 GEMMs (offset + Y; K-split x4, N-split x2, compile-time NT)
    k_gemms1<<<3136, 256, 0, stream>>>(Xf, OWbf, W1f, Zp, Y1);

    // 3) stage-1 combine (fused sparams_z1, sums 4 partials) -> Xbf1
    k_combine1<<<256, 256, 0, stream>>>(Y1, Zp, ob1, b1, Xbf1, Xbf1 + 65536);

    // 4) stage-2 GEMMs (offmfma + ygemm, merged)
    k_gemms23<64, 32><<<dim3(16, 53), 256, 0, stream>>>(
        Xbf1, OWf2, W2f, off2, Y2, 16, 32, 32, 64, 1024, 65536);

    // 5) stage-2 combine -> Xbf2
    k_combine23<32, false><<<512, 256, 0, stream>>>(
        Y2, off2, ob2, b2, Xbf2, Xbf2 + 131072, nullptr, nullptr, 4096, 1024, 16, 32, 32, 64);

    // 6) stage-3 GEMMs
    k_gemms23<32, 16><<<dim3(64, 53), 256, 0, stream>>>(
        Xbf2, OWf3, W3f, off3, Y3, 32, 64, 64, 128, 4096, 131072);

    // 7) stage-3 combine + Y4 -> Xbf3, Y4
    k_combine23<16, true><<<1024, 256, 0, stream>>>(
        Y3, off3, ob3, b3, Xbf3, Xbf3 + 262144, w4, Y4, 16384, 4096, 32, 64, 64, 128);

    // 8) stage-4 fused: offsets (MFMA->LDS) + sparams + dconv -> out
    k_stage4<<<dim3(256, 4), 256, 0, stream>>>(Xbf3, OWf4, Y4, ob4, b4, out, 262144);
}